// Round 1
// baseline (440.562 us; speedup 1.0000x reference)
//
#include <hip/hip_runtime.h>
#include <hip/hip_bf16.h>
#include <math.h>

typedef __attribute__((ext_vector_type(4))) float f32x4;
typedef __attribute__((ext_vector_type(8))) short bf16x8;

#define T_TOK 2048
#define H_DIM 1024
#define I_DIM 2048
#define E_NUM 8

// RNE float -> bf16 (bit trick; avoids header/aliasing concerns)
__device__ inline unsigned short f2bf(float f) {
  union { float f; unsigned int u; } v; v.f = f;
  unsigned int r = v.u + 0x7fffu + ((v.u >> 16) & 1u);
  return (unsigned short)(r >> 16);
}

__global__ void zero32(int* p) { p[threadIdx.x] = 0; }

// ---------------- gating: fp32 logits, top-2, two-way softmax weights ----------------
__global__ __launch_bounds__(256) void gate_kernel(
    const float* __restrict__ x, const float* __restrict__ gw, const float* __restrict__ gb,
    int* __restrict__ counts, int* __restrict__ rec_e, float* __restrict__ rec_w)
{
  int wv = threadIdx.x >> 6, lane = threadIdx.x & 63;
  int t = blockIdx.x * 4 + wv;
  const float* xr = x + (size_t)t * H_DIM;
  float acc[8];
#pragma unroll
  for (int e = 0; e < 8; ++e) acc[e] = 0.f;
  for (int i = 0; i < H_DIM / 64; ++i) {
    int h = i * 64 + lane;
    float xv = xr[h];
    const float4* g = (const float4*)(gw + (size_t)h * 8);
    float4 g0 = g[0], g1 = g[1];
    acc[0] += xv * g0.x; acc[1] += xv * g0.y; acc[2] += xv * g0.z; acc[3] += xv * g0.w;
    acc[4] += xv * g1.x; acc[5] += xv * g1.y; acc[6] += xv * g1.z; acc[7] += xv * g1.w;
  }
#pragma unroll
  for (int s = 1; s < 64; s <<= 1) {
#pragma unroll
    for (int e = 0; e < 8; ++e) acc[e] += __shfl_xor(acc[e], s);
  }
  if (lane == 0) {
    float l[8];
#pragma unroll
    for (int e = 0; e < 8; ++e) l[e] = acc[e] + gb[e];
    int e0 = 0;
    for (int e = 1; e < 8; ++e) if (l[e] > l[e0]) e0 = e;      // ties -> lowest idx, matches jax
    int e1 = (e0 == 0) ? 1 : 0;
    for (int e = 0; e < 8; ++e) if (e != e0 && l[e] > l[e1]) e1 = e;
    // renormalized top-2 softmax == 2-way softmax of the two logits
    float w0 = 1.f / (1.f + expf(l[e1] - l[e0]));
    rec_e[t * 2]     = e0; rec_e[t * 2 + 1] = e1;
    rec_w[t * 2]     = w0; rec_w[t * 2 + 1] = 1.f - w0;
    atomicAdd(&counts[e0], 1);
    atomicAdd(&counts[e1], 1);
  }
}

// ---------------- build contiguous per-expert token lists ----------------
__global__ void fill_kernel(const int* __restrict__ counts, int* __restrict__ fill,
                            const int* __restrict__ rec_e, const float* __restrict__ rec_w,
                            int* __restrict__ list_tok, float* __restrict__ list_w)
{
  int t = blockIdx.x * 256 + threadIdx.x;
  int c[8];
#pragma unroll
  for (int i = 0; i < 8; ++i) c[i] = counts[i];
#pragma unroll
  for (int k = 0; k < 2; ++k) {
    int e = rec_e[t * 2 + k];
    int b = 0;
    for (int i = 0; i < 8; ++i) if (i < e) b += c[i];
    int pos = atomicAdd(&fill[e], 1);
    list_tok[b + pos] = (t << 1) | k;
    list_w[b + pos]   = rec_w[t * 2 + k];
  }
}

// ---------------- x fp32 -> bf16 ----------------
__global__ __launch_bounds__(256) void cast_x(const float* __restrict__ in,
                                              unsigned short* __restrict__ outp)
{
  int i = (blockIdx.x * 256 + threadIdx.x) * 4;
  float4 v = *(const float4*)(in + i);
  ushort4 o;
  o.x = f2bf(v.x); o.y = f2bf(v.y); o.z = f2bf(v.z); o.w = f2bf(v.w);
  *(ushort4*)(outp + i) = o;
}

// ---------------- weight fp32 [E][R][C] -> bf16 [E][C][R] (cast + transpose) ----------------
__global__ __launch_bounds__(256) void transpose_cast(
    const float* __restrict__ in, unsigned short* __restrict__ outp, int R, int C)
{
  __shared__ float tile[32][33];
  int e = blockIdx.z;
  const float* ip = in + (size_t)e * R * C;
  unsigned short* op = outp + (size_t)e * R * C;
  int c0 = blockIdx.x * 32, r0 = blockIdx.y * 32;
  int tx = threadIdx.x & 31, ty = threadIdx.x >> 5;  // ty 0..7
#pragma unroll
  for (int j = 0; j < 4; ++j)
    tile[ty + 8 * j][tx] = ip[(size_t)(r0 + ty + 8 * j) * C + c0 + tx];
  __syncthreads();
#pragma unroll
  for (int j = 0; j < 4; ++j)
    op[(size_t)(c0 + ty + 8 * j) * R + r0 + tx] = f2bf(tile[tx][ty + 8 * j]);
}

// ---------------- GEMM1: h = silu(x@w1) * (x@w3), gathered rows, K=H ----------------
// A: xb[tok][k] (bf16, k contig). B: w1t/w3t[e][i][k] (bf16, k contig).
// Tile: 64 slots x 64 i, BK=32, 4 waves (wave = 16-row strip), dual acc.
__global__ __launch_bounds__(256) void gemm1(
    const unsigned short* __restrict__ xb,
    const unsigned short* __restrict__ w1t,
    const unsigned short* __restrict__ w3t,
    const int* __restrict__ counts,
    const int* __restrict__ list_tok,
    unsigned short* __restrict__ hbuf)
{
  int e = blockIdx.z;
  int nbase = 0;
  for (int i = 0; i < 8; ++i) if (i < e) nbase += counts[i];
  int n_e = counts[e];
  int t0 = blockIdx.y * 64;
  if (t0 >= n_e) return;
  int i0 = blockIdx.x * 64;

  __shared__ unsigned short As[64][40];   // +8 pad: 80B row stride, conflict-light b128 reads
  __shared__ unsigned short B1s[64][40];
  __shared__ unsigned short B3s[64][40];

  int tid = threadIdx.x;
  int row = tid >> 2;
  int seg = (tid & 3) << 3;  // 0,8,16,24 (bf16 elements)

  int sr = t0 + row;
  int tok = 0;
  if (sr < n_e) tok = list_tok[nbase + sr] >> 1;
  const unsigned short* arow  = xb  + (size_t)tok * H_DIM + seg;
  const unsigned short* b1row = w1t + ((size_t)e * I_DIM + i0 + row) * H_DIM + seg;
  const unsigned short* b3row = w3t + ((size_t)e * I_DIM + i0 + row) * H_DIM + seg;

  int wv = tid >> 6, lane = tid & 63, lm = lane & 15, lq = lane >> 4;

  f32x4 acc1[4], acc3[4];
#pragma unroll
  for (int j = 0; j < 4; ++j) { acc1[j] = (f32x4){0.f,0.f,0.f,0.f}; acc3[j] = (f32x4){0.f,0.f,0.f,0.f}; }

  for (int kb = 0; kb < H_DIM; kb += 32) {
    uint4 av  = *(const uint4*)(arow + kb);
    uint4 b1v = *(const uint4*)(b1row + kb);
    uint4 b3v = *(const uint4*)(b3row + kb);
    __syncthreads();
    *(uint4*)&As[row][seg]  = av;
    *(uint4*)&B1s[row][seg] = b1v;
    *(uint4*)&B3s[row][seg] = b3v;
    __syncthreads();
    bf16x8 af = *(const bf16x8*)&As[wv * 16 + lm][lq * 8];
#pragma unroll
    for (int j = 0; j < 4; ++j) {
      bf16x8 b1 = *(const bf16x8*)&B1s[j * 16 + lm][lq * 8];
      bf16x8 b3 = *(const bf16x8*)&B3s[j * 16 + lm][lq * 8];
      acc1[j] = __builtin_amdgcn_mfma_f32_16x16x32_bf16(af, b1, acc1[j], 0, 0, 0);
      acc3[j] = __builtin_amdgcn_mfma_f32_16x16x32_bf16(af, b3, acc3[j], 0, 0, 0);
    }
  }
  // epilogue: C/D layout col=lane&15, row=(lane>>4)*4+reg  [m89/m91 verified]
#pragma unroll
  for (int j = 0; j < 4; ++j) {
#pragma unroll
    for (int r = 0; r < 4; ++r) {
      int m = wv * 16 + lq * 4 + r;
      int srow = t0 + m;
      if (srow < n_e) {
        float a = acc1[j][r], b = acc3[j][r];
        float hv = (a / (1.f + __expf(-a))) * b;  // silu(a)*b
        hbuf[(size_t)(nbase + srow) * I_DIM + i0 + j * 16 + lm] = f2bf(hv);
      }
    }
  }
}

// ---------------- GEMM2: y = h @ w2, scaled by routing weight, scatter to partial ----------------
__global__ __launch_bounds__(256) void gemm2(
    const unsigned short* __restrict__ hbuf,
    const unsigned short* __restrict__ w2t,
    const int* __restrict__ counts,
    const int* __restrict__ list_tok,
    const float* __restrict__ list_w,
    float* __restrict__ partial)
{
  int e = blockIdx.z;
  int nbase = 0;
  for (int i = 0; i < 8; ++i) if (i < e) nbase += counts[i];
  int n_e = counts[e];
  int t0 = blockIdx.y * 64;
  if (t0 >= n_e) return;
  int h0 = blockIdx.x * 64;

  __shared__ unsigned short As[64][40];
  __shared__ unsigned short Bs[64][40];

  int tid = threadIdx.x;
  int row = tid >> 2;
  int seg = (tid & 3) << 3;

  int sr = t0 + row;
  int arowi = nbase + ((sr < n_e) ? sr : 0);
  const unsigned short* arow = hbuf + (size_t)arowi * I_DIM + seg;
  const unsigned short* brow = w2t + ((size_t)e * H_DIM + h0 + row) * I_DIM + seg;

  int wv = tid >> 6, lane = tid & 63, lm = lane & 15, lq = lane >> 4;
  f32x4 acc[4];
#pragma unroll
  for (int j = 0; j < 4; ++j) acc[j] = (f32x4){0.f,0.f,0.f,0.f};

  for (int kb = 0; kb < I_DIM; kb += 32) {
    uint4 av = *(const uint4*)(arow + kb);
    uint4 bv = *(const uint4*)(brow + kb);
    __syncthreads();
    *(uint4*)&As[row][seg] = av;
    *(uint4*)&Bs[row][seg] = bv;
    __syncthreads();
    bf16x8 af = *(const bf16x8*)&As[wv * 16 + lm][lq * 8];
#pragma unroll
    for (int j = 0; j < 4; ++j) {
      bf16x8 bf_ = *(const bf16x8*)&Bs[j * 16 + lm][lq * 8];
      acc[j] = __builtin_amdgcn_mfma_f32_16x16x32_bf16(af, bf_, acc[j], 0, 0, 0);
    }
  }

  int entv[4]; float wtv[4];
#pragma unroll
  for (int r = 0; r < 4; ++r) {
    int srow = t0 + wv * 16 + lq * 4 + r;
    if (srow < n_e) { entv[r] = list_tok[nbase + srow]; wtv[r] = list_w[nbase + srow]; }
    else entv[r] = -1;
  }
#pragma unroll
  for (int j = 0; j < 4; ++j) {
#pragma unroll
    for (int r = 0; r < 4; ++r) {
      if (entv[r] >= 0) {
        int t = entv[r] >> 1, kk = entv[r] & 1;
        partial[((size_t)kk * T_TOK + t) * H_DIM + h0 + j * 16 + lm] = acc[j][r] * wtv[r];
      }
    }
  }
}

// ---------------- out = partial[0] + partial[1] ----------------
__global__ __launch_bounds__(256) void combine(const float* __restrict__ partial,
                                               float* __restrict__ out)
{
  int i = (blockIdx.x * 256 + threadIdx.x) * 4;
  float4 a = *(const float4*)(partial + i);
  float4 b = *(const float4*)(partial + (size_t)T_TOK * H_DIM + i);
  float4 o;
  o.x = a.x + b.x; o.y = a.y + b.y; o.z = a.z + b.z; o.w = a.w + b.w;
  *(float4*)(out + i) = o;
}

extern "C" void kernel_launch(void* const* d_in, const int* in_sizes, int n_in,
                              void* d_out, int out_size, void* d_ws, size_t ws_size,
                              hipStream_t stream) {
  const float* x  = (const float*)d_in[0];
  const float* gw = (const float*)d_in[1];
  const float* gb = (const float*)d_in[2];
  const float* w1 = (const float*)d_in[3];
  const float* w3 = (const float*)d_in[4];
  const float* w2 = (const float*)d_in[5];
  float* out = (float*)d_out;

  char* ws = (char*)d_ws;
  // small control block
  int*   counts   = (int*)(ws);            // 8 ints @ 0
  int*   fillc    = (int*)(ws + 64);       // 8 ints @ 64
  int*   rec_e    = (int*)(ws + 128);      // 4096 ints
  float* rec_w    = (float*)(ws + 16512);  // 4096 floats
  int*   list_tok = (int*)(ws + 32896);    // 4096 ints
  float* list_w   = (float*)(ws + 49280);  // 4096 floats
  const size_t MB = 1024ull * 1024ull;
  unsigned short* xb   = (unsigned short*)(ws + 1 * MB);    // 4 MB
  unsigned short* w1t  = (unsigned short*)(ws + 5 * MB);    // 32 MB  [E][I][H]
  unsigned short* w3t  = (unsigned short*)(ws + 37 * MB);   // 32 MB  [E][I][H]
  unsigned short* w2t  = (unsigned short*)(ws + 69 * MB);   // 32 MB  [E][H][I]
  unsigned short* hbuf = (unsigned short*)(ws + 101 * MB);  // 16 MB  [4096][I]
  float* partial       = (float*)(ws + 117 * MB);           // 16 MB  [2][T][H]

  zero32<<<1, 32, 0, stream>>>(counts);
  gate_kernel<<<T_TOK / 4, 256, 0, stream>>>(x, gw, gb, counts, rec_e, rec_w);
  fill_kernel<<<T_TOK / 256, 256, 0, stream>>>(counts, fillc, rec_e, rec_w, list_tok, list_w);
  cast_x<<<(T_TOK * H_DIM) / (256 * 4), 256, 0, stream>>>(x, xb);
  dim3 tg13(I_DIM / 32, H_DIM / 32, E_NUM);  // w1/w3: R=H, C=I
  transpose_cast<<<tg13, 256, 0, stream>>>(w1, w1t, H_DIM, I_DIM);
  transpose_cast<<<tg13, 256, 0, stream>>>(w3, w3t, H_DIM, I_DIM);
  dim3 tg2(H_DIM / 32, I_DIM / 32, E_NUM);   // w2: R=I, C=H
  transpose_cast<<<tg2, 256, 0, stream>>>(w2, w2t, I_DIM, H_DIM);
  gemm1<<<dim3(I_DIM / 64, T_TOK / 64, E_NUM), 256, 0, stream>>>(xb, w1t, w3t, counts, list_tok, hbuf);
  gemm2<<<dim3(H_DIM / 64, T_TOK / 64, E_NUM), 256, 0, stream>>>(hbuf, w2t, counts, list_tok, list_w, partial);
  combine<<<(T_TOK * H_DIM) / (256 * 4), 256, 0, stream>>>(partial, out);
}

// Round 2
// 380.786 us; speedup vs baseline: 1.1570x; 1.1570x over previous
//
#include <hip/hip_runtime.h>
#include <hip/hip_bf16.h>
#include <math.h>

typedef __attribute__((ext_vector_type(4))) float f32x4;
typedef __attribute__((ext_vector_type(8))) short bf16x8;

#define T_TOK 2048
#define H_DIM 1024
#define I_DIM 2048
#define E_NUM 8

// RNE float -> bf16
__device__ inline unsigned short f2bf(float f) {
  union { float f; unsigned int u; } v; v.f = f;
  unsigned int r = v.u + 0x7fffu + ((v.u >> 16) & 1u);
  return (unsigned short)(r >> 16);
}

// async global->LDS, 16 bytes per lane; lds dest = wave-uniform base + lane*16
__device__ inline void gld16(const void* g, void* l) {
  __builtin_amdgcn_global_load_lds((const __attribute__((address_space(1))) void*)g,
                                   (__attribute__((address_space(3))) void*)l, 16, 0, 0);
}

// ---------------- gating: fp32 logits, top-2, two-way softmax weights ----------------
__global__ __launch_bounds__(256) void gate_kernel(
    const float* __restrict__ x, const float* __restrict__ gw, const float* __restrict__ gb,
    int* __restrict__ rec_e, float* __restrict__ rec_w)
{
  int wv = threadIdx.x >> 6, lane = threadIdx.x & 63;
  int t = blockIdx.x * 4 + wv;
  const float* xr = x + (size_t)t * H_DIM;
  float acc[8];
#pragma unroll
  for (int e = 0; e < 8; ++e) acc[e] = 0.f;
  for (int i = 0; i < H_DIM / 64; ++i) {
    int h = i * 64 + lane;
    float xv = xr[h];
    const float4* g = (const float4*)(gw + (size_t)h * 8);
    float4 g0 = g[0], g1 = g[1];
    acc[0] += xv * g0.x; acc[1] += xv * g0.y; acc[2] += xv * g0.z; acc[3] += xv * g0.w;
    acc[4] += xv * g1.x; acc[5] += xv * g1.y; acc[6] += xv * g1.z; acc[7] += xv * g1.w;
  }
#pragma unroll
  for (int s = 1; s < 64; s <<= 1) {
#pragma unroll
    for (int e = 0; e < 8; ++e) acc[e] += __shfl_xor(acc[e], s);
  }
  if (lane == 0) {
    float l[8];
#pragma unroll
    for (int e = 0; e < 8; ++e) l[e] = acc[e] + gb[e];
    int e0 = 0;
    for (int e = 1; e < 8; ++e) if (l[e] > l[e0]) e0 = e;
    int e1 = (e0 == 0) ? 1 : 0;
    for (int e = 0; e < 8; ++e) if (e != e0 && l[e] > l[e1]) e1 = e;
    float w0 = 1.f / (1.f + expf(l[e1] - l[e0]));
    rec_e[t * 2]     = e0; rec_e[t * 2 + 1] = e1;
    rec_w[t * 2]     = w0; rec_w[t * 2 + 1] = 1.f - w0;
  }
}

// ---------------- single-block routing: histogram + prefix + scatter ----------------
__global__ __launch_bounds__(256) void route_kernel(
    const int* __restrict__ rec_e, const float* __restrict__ rec_w,
    int* __restrict__ counts_g, int* __restrict__ list_tok, float* __restrict__ list_w)
{
  __shared__ int cnt[8], base[8], fill[8];
  int tid = threadIdx.x;
  if (tid < 8) { cnt[tid] = 0; fill[tid] = 0; }
  __syncthreads();
  for (int i = tid; i < T_TOK * 2; i += 256) atomicAdd(&cnt[rec_e[i]], 1);
  __syncthreads();
  if (tid == 0) {
    int b = 0;
    for (int e = 0; e < 8; ++e) { base[e] = b; b += cnt[e]; }
  }
  if (tid < 8) counts_g[tid] = cnt[tid];
  __syncthreads();
  for (int i = tid; i < T_TOK * 2; i += 256) {
    int e = rec_e[i];
    int pos = atomicAdd(&fill[e], 1);
    list_tok[base[e] + pos] = i;            // i = (t<<1)|k
    list_w[base[e] + pos]   = rec_w[i];
  }
}

// ---------------- x fp32 -> bf16 ----------------
__global__ __launch_bounds__(256) void cast_x(const float* __restrict__ in,
                                              unsigned short* __restrict__ outp)
{
  int i = (blockIdx.x * 256 + threadIdx.x) * 4;
  float4 v = *(const float4*)(in + i);
  ushort4 o;
  o.x = f2bf(v.x); o.y = f2bf(v.y); o.z = f2bf(v.z); o.w = f2bf(v.w);
  *(ushort4*)(outp + i) = o;
}

// ---------------- weight fp32 [R][C] -> bf16 [C][R]; z selects (tensor, expert) ----------------
// mode13: z<8 -> w1->w1t (e=z); z>=8 -> w3->w3t (e=z-8). R=H, C=I.
__global__ __launch_bounds__(256) void transpose13(
    const float* __restrict__ w1, const float* __restrict__ w3,
    unsigned short* __restrict__ w1t, unsigned short* __restrict__ w3t)
{
  __shared__ float tile[32][33];
  int z = blockIdx.z;
  const float* ip = (z < 8 ? w1 : w3) + (size_t)(z & 7) * H_DIM * I_DIM;
  unsigned short* op = (z < 8 ? w1t : w3t) + (size_t)(z & 7) * H_DIM * I_DIM;
  const int R = H_DIM, C = I_DIM;
  int c0 = blockIdx.x * 32, r0 = blockIdx.y * 32;
  int tx = threadIdx.x & 31, ty = threadIdx.x >> 5;
#pragma unroll
  for (int j = 0; j < 4; ++j)
    tile[ty + 8 * j][tx] = ip[(size_t)(r0 + ty + 8 * j) * C + c0 + tx];
  __syncthreads();
#pragma unroll
  for (int j = 0; j < 4; ++j)
    op[(size_t)(c0 + ty + 8 * j) * R + r0 + tx] = f2bf(tile[tx][ty + 8 * j]);
}

__global__ __launch_bounds__(256) void transpose2(
    const float* __restrict__ w2, unsigned short* __restrict__ w2t)
{
  __shared__ float tile[32][33];
  int e = blockIdx.z;
  const float* ip = w2 + (size_t)e * I_DIM * H_DIM;
  unsigned short* op = w2t + (size_t)e * I_DIM * H_DIM;
  const int R = I_DIM, C = H_DIM;
  int c0 = blockIdx.x * 32, r0 = blockIdx.y * 32;
  int tx = threadIdx.x & 31, ty = threadIdx.x >> 5;
#pragma unroll
  for (int j = 0; j < 4; ++j)
    tile[ty + 8 * j][tx] = ip[(size_t)(r0 + ty + 8 * j) * C + c0 + tx];
  __syncthreads();
#pragma unroll
  for (int j = 0; j < 4; ++j)
    op[(size_t)(c0 + ty + 8 * j) * R + r0 + tx] = f2bf(tile[tx][ty + 8 * j]);
}

// ---------------- GEMM1: 128 slots x 64 I, dual (w1,w3) acc, silu fused ----------------
// A: xb gathered rows, K=H=1024. B: w1t/w3t rows [i][k]. global_load_lds staging.
__global__ __launch_bounds__(256) void gemm1(
    const unsigned short* __restrict__ xb,
    const unsigned short* __restrict__ w1t,
    const unsigned short* __restrict__ w3t,
    const int* __restrict__ counts,
    const int* __restrict__ list_tok,
    unsigned short* __restrict__ hbuf)
{
  int e = blockIdx.z;
  int nbase = 0;
#pragma unroll
  for (int i = 0; i < 8; ++i) if (i < e) nbase += counts[i];
  int n_e = counts[e];
  int t0 = blockIdx.y * 128;
  if (t0 >= n_e) return;
  int i0 = blockIdx.x * 64;

  __shared__ __align__(16) unsigned short As[128 * 32];   // 8KB, unpadded (global_load_lds)
  __shared__ __align__(16) unsigned short B1s[64 * 32];   // 4KB
  __shared__ __align__(16) unsigned short B3s[64 * 32];   // 4KB

  int tid = threadIdx.x;
  int r = tid >> 2;            // 0..63
  int seg = (tid & 3) * 8;     // bf16 elems

  // A gather row pointers (clamped for tail rows)
  int sr0 = t0 + r;       if (sr0 >= n_e) sr0 = n_e - 1;
  int sr1 = t0 + 64 + r;  if (sr1 >= n_e) sr1 = n_e - 1;
  int tok0 = list_tok[nbase + sr0] >> 1;
  int tok1 = list_tok[nbase + sr1] >> 1;
  const char* gA0 = (const char*)(xb + (size_t)tok0 * H_DIM + seg);
  const char* gA1 = (const char*)(xb + (size_t)tok1 * H_DIM + seg);
  const char* gB1 = (const char*)(w1t + ((size_t)e * I_DIM + i0 + r) * H_DIM + seg);
  const char* gB3 = (const char*)(w3t + ((size_t)e * I_DIM + i0 + r) * H_DIM + seg);

  char* lA0 = (char*)As + tid * 16;
  char* lA1 = (char*)As + 4096 + tid * 16;
  char* lB1 = (char*)B1s + tid * 16;
  char* lB3 = (char*)B3s + tid * 16;

  int w = tid >> 6, lane = tid & 63, lm = lane & 15, lq = lane >> 4;
  int wm = w & 1, wn = w >> 1;  // wave tile: m-off wm*64, n-off wn*32

  f32x4 acc1[4][2], acc3[4][2];
#pragma unroll
  for (int i = 0; i < 4; ++i)
#pragma unroll
    for (int j = 0; j < 2; ++j) { acc1[i][j] = (f32x4){0,0,0,0}; acc3[i][j] = (f32x4){0,0,0,0}; }

  for (int kb = 0; kb < H_DIM; kb += 32) {
    __syncthreads();
    gld16(gA0 + kb * 2, lA0);
    gld16(gA1 + kb * 2, lA1);
    gld16(gB1 + kb * 2, lB1);
    gld16(gB3 + kb * 2, lB3);
    __syncthreads();
    bf16x8 a[4], b1[2], b3[2];
#pragma unroll
    for (int i = 0; i < 4; ++i)
      a[i] = *(const bf16x8*)((const char*)As + 2 * ((wm * 64 + i * 16 + lm) * 32 + lq * 8));
#pragma unroll
    for (int j = 0; j < 2; ++j) {
      b1[j] = *(const bf16x8*)((const char*)B1s + 2 * ((wn * 32 + j * 16 + lm) * 32 + lq * 8));
      b3[j] = *(const bf16x8*)((const char*)B3s + 2 * ((wn * 32 + j * 16 + lm) * 32 + lq * 8));
    }
#pragma unroll
    for (int i = 0; i < 4; ++i)
#pragma unroll
      for (int j = 0; j < 2; ++j) {
        acc1[i][j] = __builtin_amdgcn_mfma_f32_16x16x32_bf16(a[i], b1[j], acc1[i][j], 0, 0, 0);
        acc3[i][j] = __builtin_amdgcn_mfma_f32_16x16x32_bf16(a[i], b3[j], acc3[i][j], 0, 0, 0);
      }
  }

  // epilogue: D row = lq*4+reg, col = lm; silu(acc1)*acc3 -> hbuf
#pragma unroll
  for (int i = 0; i < 4; ++i) {
#pragma unroll
    for (int rr = 0; rr < 4; ++rr) {
      int slot = t0 + wm * 64 + i * 16 + lq * 4 + rr;
      if (slot < n_e) {
#pragma unroll
        for (int j = 0; j < 2; ++j) {
          float g = acc1[i][j][rr], u = acc3[i][j][rr];
          float hv = (g / (1.f + __expf(-g))) * u;
          hbuf[(size_t)(nbase + slot) * I_DIM + i0 + wn * 32 + j * 16 + lm] = f2bf(hv);
        }
      }
    }
  }
}

// ---------------- GEMM2: 64 slots x 128 H, K=I=2048, scaled scatter ----------------
__global__ __launch_bounds__(256) void gemm2(
    const unsigned short* __restrict__ hbuf,
    const unsigned short* __restrict__ w2t,
    const int* __restrict__ counts,
    const int* __restrict__ list_tok,
    const float* __restrict__ list_w,
    float* __restrict__ partial)
{
  int e = blockIdx.z;
  int nbase = 0;
#pragma unroll
  for (int i = 0; i < 8; ++i) if (i < e) nbase += counts[i];
  int n_e = counts[e];
  int t0 = blockIdx.y * 64;
  if (t0 >= n_e) return;
  int h0 = blockIdx.x * 128;

  __shared__ __align__(16) unsigned short As[64 * 32];    // 4KB
  __shared__ __align__(16) unsigned short Bs[128 * 32];   // 8KB

  int tid = threadIdx.x;
  int r = tid >> 2;
  int seg = (tid & 3) * 8;

  int sr = t0 + r; if (sr >= n_e) sr = n_e - 1;
  const char* gA  = (const char*)(hbuf + (size_t)(nbase + sr) * I_DIM + seg);
  const char* gB0 = (const char*)(w2t + ((size_t)e * H_DIM + h0 + r) * I_DIM + seg);
  const char* gB1 = (const char*)(w2t + ((size_t)e * H_DIM + h0 + 64 + r) * I_DIM + seg);

  char* lA  = (char*)As + tid * 16;
  char* lB0 = (char*)Bs + tid * 16;
  char* lB1 = (char*)Bs + 4096 + tid * 16;

  int w = tid >> 6, lane = tid & 63, lm = lane & 15, lq = lane >> 4;
  int wm = w & 1, wn = (w >> 1) * 64;  // m-off wm*32, n-off wn

  f32x4 acc[2][4];
#pragma unroll
  for (int i = 0; i < 2; ++i)
#pragma unroll
    for (int j = 0; j < 4; ++j) acc[i][j] = (f32x4){0,0,0,0};

  for (int kb = 0; kb < I_DIM; kb += 32) {
    __syncthreads();
    gld16(gA + kb * 2, lA);
    gld16(gB0 + kb * 2, lB0);
    gld16(gB1 + kb * 2, lB1);
    __syncthreads();
    bf16x8 a[2], b[4];
#pragma unroll
    for (int i = 0; i < 2; ++i)
      a[i] = *(const bf16x8*)((const char*)As + 2 * ((wm * 32 + i * 16 + lm) * 32 + lq * 8));
#pragma unroll
    for (int j = 0; j < 4; ++j)
      b[j] = *(const bf16x8*)((const char*)Bs + 2 * ((wn + j * 16 + lm) * 32 + lq * 8));
#pragma unroll
    for (int i = 0; i < 2; ++i)
#pragma unroll
      for (int j = 0; j < 4; ++j)
        acc[i][j] = __builtin_amdgcn_mfma_f32_16x16x32_bf16(a[i], b[j], acc[i][j], 0, 0, 0);
  }

  int entv[2][4]; float wtv[2][4];
#pragma unroll
  for (int i = 0; i < 2; ++i)
#pragma unroll
    for (int rr = 0; rr < 4; ++rr) {
      int slot = t0 + wm * 32 + i * 16 + lq * 4 + rr;
      if (slot < n_e) { entv[i][rr] = list_tok[nbase + slot]; wtv[i][rr] = list_w[nbase + slot]; }
      else entv[i][rr] = -1;
    }
#pragma unroll
  for (int i = 0; i < 2; ++i)
#pragma unroll
    for (int j = 0; j < 4; ++j)
#pragma unroll
      for (int rr = 0; rr < 4; ++rr) {
        if (entv[i][rr] >= 0) {
          int t = entv[i][rr] >> 1, kk = entv[i][rr] & 1;
          partial[((size_t)kk * T_TOK + t) * H_DIM + h0 + wn + j * 16 + lm] = acc[i][j][rr] * wtv[i][rr];
        }
      }
}

// ---------------- out = partial[0] + partial[1] ----------------
__global__ __launch_bounds__(256) void combine(const float* __restrict__ partial,
                                               float* __restrict__ out)
{
  int i = (blockIdx.x * 256 + threadIdx.x) * 4;
  float4 a = *(const float4*)(partial + i);
  float4 b = *(const float4*)(partial + (size_t)T_TOK * H_DIM + i);
  float4 o;
  o.x = a.x + b.x; o.y = a.y + b.y; o.z = a.z + b.z; o.w = a.w + b.w;
  *(float4*)(out + i) = o;
}

extern "C" void kernel_launch(void* const* d_in, const int* in_sizes, int n_in,
                              void* d_out, int out_size, void* d_ws, size_t ws_size,
                              hipStream_t stream) {
  const float* x  = (const float*)d_in[0];
  const float* gw = (const float*)d_in[1];
  const float* gb = (const float*)d_in[2];
  const float* w1 = (const float*)d_in[3];
  const float* w3 = (const float*)d_in[4];
  const float* w2 = (const float*)d_in[5];
  float* out = (float*)d_out;

  char* ws = (char*)d_ws;
  int*   counts   = (int*)(ws);            // 8 ints
  int*   rec_e    = (int*)(ws + 128);      // 4096 ints
  float* rec_w    = (float*)(ws + 16512);  // 4096 floats
  int*   list_tok = (int*)(ws + 32896);    // 4096 ints
  float* list_w   = (float*)(ws + 49280);  // 4096 floats
  const size_t MB = 1024ull * 1024ull;
  unsigned short* xb   = (unsigned short*)(ws + 1 * MB);    // 4 MB
  unsigned short* w1t  = (unsigned short*)(ws + 5 * MB);    // 32 MB  [E][I][H]
  unsigned short* w3t  = (unsigned short*)(ws + 37 * MB);   // 32 MB  [E][I][H]
  unsigned short* w2t  = (unsigned short*)(ws + 69 * MB);   // 32 MB  [E][H][I]
  unsigned short* hbuf = (unsigned short*)(ws + 101 * MB);  // 16 MB  [4096][I]
  float* partial       = (float*)(ws + 117 * MB);           // 16 MB  [2][T][H]

  gate_kernel<<<T_TOK / 4, 256, 0, stream>>>(x, gw, gb, rec_e, rec_w);
  route_kernel<<<1, 256, 0, stream>>>(rec_e, rec_w, counts, list_tok, list_w);
  cast_x<<<(T_TOK * H_DIM) / (256 * 4), 256, 0, stream>>>(x, xb);
  transpose13<<<dim3(I_DIM / 32, H_DIM / 32, 16), 256, 0, stream>>>(w1, w3, w1t, w3t);
  transpose2<<<dim3(H_DIM / 32, I_DIM / 32, 8), 256, 0, stream>>>(w2, w2t);
  gemm1<<<dim3(I_DIM / 64, 16, E_NUM), 256, 0, stream>>>(xb, w1t, w3t, counts, list_tok, hbuf);
  gemm2<<<dim3(H_DIM / 128, 32, E_NUM), 256, 0, stream>>>(hbuf, w2t, counts, list_tok, list_w, partial);
  combine<<<(T_TOK * H_DIM) / (256 * 4), 256, 0, stream>>>(partial, out);
}

// Round 3
// 367.680 us; speedup vs baseline: 1.1982x; 1.0356x over previous
//
#include <hip/hip_runtime.h>
#include <hip/hip_bf16.h>
#include <math.h>

typedef __attribute__((ext_vector_type(4))) float f32x4;
typedef __attribute__((ext_vector_type(8))) short bf16x8;

#define T_TOK 2048
#define H_DIM 1024
#define I_DIM 2048
#define E_NUM 8

// RNE float -> bf16
__device__ inline unsigned short f2bf(float f) {
  union { float f; unsigned int u; } v; v.f = f;
  unsigned int r = v.u + 0x7fffu + ((v.u >> 16) & 1u);
  return (unsigned short)(r >> 16);
}

// async global->LDS, 16 bytes per lane; lds dest = wave-uniform base + lane*16
__device__ inline void gld16(const void* g, void* l) {
  __builtin_amdgcn_global_load_lds((const __attribute__((address_space(1))) void*)g,
                                   (__attribute__((address_space(3))) void*)l, 16, 0, 0);
}

// ---------------- gating + x cast fused ----------------
__global__ __launch_bounds__(256) void gate_kernel(
    const float* __restrict__ x, const float* __restrict__ gw, const float* __restrict__ gb,
    int* __restrict__ rec_e, float* __restrict__ rec_w, unsigned short* __restrict__ xb)
{
  int wv = threadIdx.x >> 6, lane = threadIdx.x & 63;
  int t = blockIdx.x * 4 + wv;
  const float* xr = x + (size_t)t * H_DIM;
  unsigned short* xo = xb + (size_t)t * H_DIM;
  float acc[8];
#pragma unroll
  for (int e = 0; e < 8; ++e) acc[e] = 0.f;
  for (int i = 0; i < H_DIM / 64; ++i) {
    int h = i * 64 + lane;
    float xv = xr[h];
    xo[h] = f2bf(xv);
    const float4* g = (const float4*)(gw + (size_t)h * 8);
    float4 g0 = g[0], g1 = g[1];
    acc[0] += xv * g0.x; acc[1] += xv * g0.y; acc[2] += xv * g0.z; acc[3] += xv * g0.w;
    acc[4] += xv * g1.x; acc[5] += xv * g1.y; acc[6] += xv * g1.z; acc[7] += xv * g1.w;
  }
#pragma unroll
  for (int s = 1; s < 64; s <<= 1) {
#pragma unroll
    for (int e = 0; e < 8; ++e) acc[e] += __shfl_xor(acc[e], s);
  }
  if (lane == 0) {
    float l[8];
#pragma unroll
    for (int e = 0; e < 8; ++e) l[e] = acc[e] + gb[e];
    int e0 = 0;
    for (int e = 1; e < 8; ++e) if (l[e] > l[e0]) e0 = e;
    int e1 = (e0 == 0) ? 1 : 0;
    for (int e = 0; e < 8; ++e) if (e != e0 && l[e] > l[e1]) e1 = e;
    float w0 = 1.f / (1.f + expf(l[e1] - l[e0]));
    rec_e[t * 2]     = e0; rec_e[t * 2 + 1] = e1;
    rec_w[t * 2]     = w0; rec_w[t * 2 + 1] = 1.f - w0;
  }
}

// ---------------- single-block routing ----------------
__global__ __launch_bounds__(256) void route_kernel(
    const int* __restrict__ rec_e, const float* __restrict__ rec_w,
    int* __restrict__ counts_g, int* __restrict__ list_tok, float* __restrict__ list_w)
{
  __shared__ int cnt[8], base[8], fill[8];
  int tid = threadIdx.x;
  if (tid < 8) { cnt[tid] = 0; fill[tid] = 0; }
  __syncthreads();
  int e_loc[16];
  int c_loc[8];
#pragma unroll
  for (int e = 0; e < 8; ++e) c_loc[e] = 0;
#pragma unroll
  for (int it = 0; it < 16; ++it) {
    e_loc[it] = rec_e[it * 256 + tid];
    c_loc[e_loc[it] & 7]++;
  }
#pragma unroll
  for (int e = 0; e < 8; ++e) if (c_loc[e]) atomicAdd(&cnt[e], c_loc[e]);
  __syncthreads();
  if (tid == 0) {
    int b = 0;
    for (int e = 0; e < 8; ++e) { base[e] = b; b += cnt[e]; }
  }
  if (tid < 8) counts_g[tid] = cnt[tid];
  __syncthreads();
#pragma unroll
  for (int it = 0; it < 16; ++it) {
    int i = it * 256 + tid;
    int e = e_loc[it] & 7;
    int pos = atomicAdd(&fill[e], 1);
    list_tok[base[e] + pos] = i;            // i = (t<<1)|k
    list_w[base[e] + pos]   = rec_w[i];
  }
}

// ---------------- all weights fp32 [R][C] -> bf16 [C][R], one dispatch ----------------
// z 0..7: w1 (R=H,C=I); 8..15: w3; 16..23: w2 (R=I,C=H)
__global__ __launch_bounds__(256) void transpose_all(
    const float* __restrict__ w1, const float* __restrict__ w3, const float* __restrict__ w2,
    unsigned short* __restrict__ w1t, unsigned short* __restrict__ w3t,
    unsigned short* __restrict__ w2t)
{
  __shared__ float tile[32][33];
  int z = blockIdx.z;
  const float* ip; unsigned short* op; int R, C, c0, r0;
  if (z < 16) {
    ip = (z < 8 ? w1 : w3) + (size_t)(z & 7) * (H_DIM * I_DIM);
    op = (z < 8 ? w1t : w3t) + (size_t)(z & 7) * (H_DIM * I_DIM);
    R = H_DIM; C = I_DIM;
    c0 = blockIdx.x * 32; r0 = blockIdx.y * 32;       // x<64, y<32
  } else {
    ip = w2 + (size_t)(z - 16) * (H_DIM * I_DIM);
    op = w2t + (size_t)(z - 16) * (H_DIM * I_DIM);
    R = I_DIM; C = H_DIM;
    int t2 = blockIdx.x + 64 * blockIdx.y;            // 0..2047
    c0 = (t2 & 31) * 32; r0 = (t2 >> 5) * 32;
  }
  int t = threadIdx.x;
  int r = t >> 3, cq = (t & 7) * 4;
  float4 v = *(const float4*)(ip + (size_t)(r0 + r) * C + c0 + cq);
  tile[r][cq] = v.x; tile[r][cq + 1] = v.y; tile[r][cq + 2] = v.z; tile[r][cq + 3] = v.w;
  __syncthreads();
  int rp = (t & 15) * 2, cc = t >> 4;  // cc 0..15
#pragma unroll
  for (int j = 0; j < 2; ++j) {
    int c = cc + 16 * j;
    ushort2 o;
    o.x = f2bf(tile[rp][c]);
    o.y = f2bf(tile[rp + 1][c]);
    *(ushort2*)(op + (size_t)(c0 + c) * R + r0 + rp) = o;
  }
}

// ---------------- GEMM1: 128 slots x 64 I, dual (w1,w3) acc, silu fused ----------------
__global__ __launch_bounds__(256) void gemm1(
    const unsigned short* __restrict__ xb,
    const unsigned short* __restrict__ w1t,
    const unsigned short* __restrict__ w3t,
    const int* __restrict__ counts,
    const int* __restrict__ list_tok,
    unsigned short* __restrict__ hbuf)
{
  int e = blockIdx.z;
  int nbase = 0;
#pragma unroll
  for (int i = 0; i < 8; ++i) if (i < e) nbase += counts[i];
  int n_e = counts[e];
  int t0 = blockIdx.y * 128;
  if (t0 >= n_e) return;
  int i0 = blockIdx.x * 64;

  __shared__ __align__(16) unsigned short As[128 * 32];   // 8KB
  __shared__ __align__(16) unsigned short B1s[64 * 32];   // 4KB
  __shared__ __align__(16) unsigned short B3s[64 * 32];   // 4KB

  int tid = threadIdx.x;
  int r = tid >> 2;
  int seg = (tid & 3) * 8;

  int sr0 = t0 + r;       if (sr0 >= n_e) sr0 = n_e - 1;
  int sr1 = t0 + 64 + r;  if (sr1 >= n_e) sr1 = n_e - 1;
  int tok0 = list_tok[nbase + sr0] >> 1;
  int tok1 = list_tok[nbase + sr1] >> 1;
  const char* gA0 = (const char*)(xb + (size_t)tok0 * H_DIM + seg);
  const char* gA1 = (const char*)(xb + (size_t)tok1 * H_DIM + seg);
  const char* gB1 = (const char*)(w1t + ((size_t)e * I_DIM + i0 + r) * H_DIM + seg);
  const char* gB3 = (const char*)(w3t + ((size_t)e * I_DIM + i0 + r) * H_DIM + seg);

  char* lA0 = (char*)As + tid * 16;
  char* lA1 = (char*)As + 4096 + tid * 16;
  char* lB1 = (char*)B1s + tid * 16;
  char* lB3 = (char*)B3s + tid * 16;

  int w = tid >> 6, lane = tid & 63, lm = lane & 15, lq = lane >> 4;
  int wm = w & 1, wn = w >> 1;

  f32x4 acc1[4][2], acc3[4][2];
#pragma unroll
  for (int i = 0; i < 4; ++i)
#pragma unroll
    for (int j = 0; j < 2; ++j) { acc1[i][j] = (f32x4){0,0,0,0}; acc3[i][j] = (f32x4){0,0,0,0}; }

  for (int kb = 0; kb < H_DIM; kb += 32) {
    __syncthreads();
    gld16(gA0 + kb * 2, lA0);
    gld16(gA1 + kb * 2, lA1);
    gld16(gB1 + kb * 2, lB1);
    gld16(gB3 + kb * 2, lB3);
    __syncthreads();
    bf16x8 a[4], b1[2], b3[2];
#pragma unroll
    for (int i = 0; i < 4; ++i)
      a[i] = *(const bf16x8*)((const char*)As + 2 * ((wm * 64 + i * 16 + lm) * 32 + lq * 8));
#pragma unroll
    for (int j = 0; j < 2; ++j) {
      b1[j] = *(const bf16x8*)((const char*)B1s + 2 * ((wn * 32 + j * 16 + lm) * 32 + lq * 8));
      b3[j] = *(const bf16x8*)((const char*)B3s + 2 * ((wn * 32 + j * 16 + lm) * 32 + lq * 8));
    }
#pragma unroll
    for (int i = 0; i < 4; ++i)
#pragma unroll
      for (int j = 0; j < 2; ++j) {
        acc1[i][j] = __builtin_amdgcn_mfma_f32_16x16x32_bf16(a[i], b1[j], acc1[i][j], 0, 0, 0);
        acc3[i][j] = __builtin_amdgcn_mfma_f32_16x16x32_bf16(a[i], b3[j], acc3[i][j], 0, 0, 0);
      }
  }

#pragma unroll
  for (int i = 0; i < 4; ++i) {
#pragma unroll
    for (int rr = 0; rr < 4; ++rr) {
      int slot = t0 + wm * 64 + i * 16 + lq * 4 + rr;
      if (slot < n_e) {
#pragma unroll
        for (int j = 0; j < 2; ++j) {
          float g = acc1[i][j][rr], u = acc3[i][j][rr];
          float hv = (g / (1.f + __expf(-g))) * u;
          hbuf[(size_t)(nbase + slot) * I_DIM + i0 + wn * 32 + j * 16 + lm] = f2bf(hv);
        }
      }
    }
  }
}

// ---------------- GEMM2: 64 slots x 128 H, split-K=2, 4-plane partial ----------------
__global__ __launch_bounds__(256) void gemm2(
    const unsigned short* __restrict__ hbuf,
    const unsigned short* __restrict__ w2t,
    const int* __restrict__ counts,
    const int* __restrict__ list_tok,
    const float* __restrict__ list_w,
    float* __restrict__ partial)
{
  int e = blockIdx.z;
  int nbase = 0;
#pragma unroll
  for (int i = 0; i < 8; ++i) if (i < e) nbase += counts[i];
  int n_e = counts[e];
  int ts = blockIdx.y >> 1, kh = blockIdx.y & 1;
  int t0 = ts * 64;
  if (t0 >= n_e) return;
  int h0 = blockIdx.x * 128;
  int k0 = kh * (I_DIM / 2);

  __shared__ __align__(16) unsigned short As[64 * 32];    // 4KB
  __shared__ __align__(16) unsigned short Bs[128 * 32];   // 8KB

  int tid = threadIdx.x;
  int r = tid >> 2;
  int seg = (tid & 3) * 8;

  int sr = t0 + r; if (sr >= n_e) sr = n_e - 1;
  const char* gA  = (const char*)(hbuf + (size_t)(nbase + sr) * I_DIM + k0 + seg);
  const char* gB0 = (const char*)(w2t + ((size_t)e * H_DIM + h0 + r) * I_DIM + k0 + seg);
  const char* gB1 = (const char*)(w2t + ((size_t)e * H_DIM + h0 + 64 + r) * I_DIM + k0 + seg);

  char* lA  = (char*)As + tid * 16;
  char* lB0 = (char*)Bs + tid * 16;
  char* lB1 = (char*)Bs + 4096 + tid * 16;

  int w = tid >> 6, lane = tid & 63, lm = lane & 15, lq = lane >> 4;
  int wm = w & 1, wn = (w >> 1) * 64;

  f32x4 acc[2][4];
#pragma unroll
  for (int i = 0; i < 2; ++i)
#pragma unroll
    for (int j = 0; j < 4; ++j) acc[i][j] = (f32x4){0,0,0,0};

  for (int kb = 0; kb < I_DIM / 2; kb += 32) {
    __syncthreads();
    gld16(gA + kb * 2, lA);
    gld16(gB0 + kb * 2, lB0);
    gld16(gB1 + kb * 2, lB1);
    __syncthreads();
    bf16x8 a[2], b[4];
#pragma unroll
    for (int i = 0; i < 2; ++i)
      a[i] = *(const bf16x8*)((const char*)As + 2 * ((wm * 32 + i * 16 + lm) * 32 + lq * 8));
#pragma unroll
    for (int j = 0; j < 4; ++j)
      b[j] = *(const bf16x8*)((const char*)Bs + 2 * ((wn + j * 16 + lm) * 32 + lq * 8));
#pragma unroll
    for (int i = 0; i < 2; ++i)
#pragma unroll
      for (int j = 0; j < 4; ++j)
        acc[i][j] = __builtin_amdgcn_mfma_f32_16x16x32_bf16(a[i], b[j], acc[i][j], 0, 0, 0);
  }

  int entv[2][4]; float wtv[2][4];
#pragma unroll
  for (int i = 0; i < 2; ++i)
#pragma unroll
    for (int rr = 0; rr < 4; ++rr) {
      int slot = t0 + wm * 32 + i * 16 + lq * 4 + rr;
      if (slot < n_e) { entv[i][rr] = list_tok[nbase + slot]; wtv[i][rr] = list_w[nbase + slot]; }
      else entv[i][rr] = -1;
    }
#pragma unroll
  for (int i = 0; i < 2; ++i)
#pragma unroll
    for (int j = 0; j < 4; ++j)
#pragma unroll
      for (int rr = 0; rr < 4; ++rr) {
        if (entv[i][rr] >= 0) {
          int t = entv[i][rr] >> 1, kk = entv[i][rr] & 1;
          int plane = kh * 2 + kk;
          partial[((size_t)plane * T_TOK + t) * H_DIM + h0 + wn + j * 16 + lm] =
              acc[i][j][rr] * wtv[i][rr];
        }
      }
}

// ---------------- out = sum of 4 partial planes ----------------
__global__ __launch_bounds__(256) void combine4(const float* __restrict__ partial,
                                                float* __restrict__ out)
{
  const size_t P = (size_t)T_TOK * H_DIM;
  int i = (blockIdx.x * 256 + threadIdx.x) * 4;
  float4 a = *(const float4*)(partial + i);
  float4 b = *(const float4*)(partial + P + i);
  float4 c = *(const float4*)(partial + 2 * P + i);
  float4 d = *(const float4*)(partial + 3 * P + i);
  float4 o;
  o.x = a.x + b.x + c.x + d.x;
  o.y = a.y + b.y + c.y + d.y;
  o.z = a.z + b.z + c.z + d.z;
  o.w = a.w + b.w + c.w + d.w;
  *(float4*)(out + i) = o;
}

extern "C" void kernel_launch(void* const* d_in, const int* in_sizes, int n_in,
                              void* d_out, int out_size, void* d_ws, size_t ws_size,
                              hipStream_t stream) {
  const float* x  = (const float*)d_in[0];
  const float* gw = (const float*)d_in[1];
  const float* gb = (const float*)d_in[2];
  const float* w1 = (const float*)d_in[3];
  const float* w3 = (const float*)d_in[4];
  const float* w2 = (const float*)d_in[5];
  float* out = (float*)d_out;

  char* ws = (char*)d_ws;
  int*   counts   = (int*)(ws);            // 8 ints
  int*   rec_e    = (int*)(ws + 128);      // 4096 ints
  float* rec_w    = (float*)(ws + 16512);  // 4096 floats
  int*   list_tok = (int*)(ws + 32896);    // 4096 ints
  float* list_w   = (float*)(ws + 49280);  // 4096 floats
  const size_t MB = 1024ull * 1024ull;
  unsigned short* xb   = (unsigned short*)(ws + 1 * MB);    // 4 MB
  unsigned short* w1t  = (unsigned short*)(ws + 5 * MB);    // 32 MB  [E][I][H]
  float* partial       = (float*)(ws + 5 * MB);             // 32 MB  [4][T][H] (aliases w1t; w1t dead after gemm1)
  unsigned short* w3t  = (unsigned short*)(ws + 37 * MB);   // 32 MB  [E][I][H]
  unsigned short* w2t  = (unsigned short*)(ws + 69 * MB);   // 32 MB  [E][H][I]
  unsigned short* hbuf = (unsigned short*)(ws + 101 * MB);  // 16 MB  [4096][I]

  gate_kernel<<<T_TOK / 4, 256, 0, stream>>>(x, gw, gb, rec_e, rec_w, xb);
  route_kernel<<<1, 256, 0, stream>>>(rec_e, rec_w, counts, list_tok, list_w);
  transpose_all<<<dim3(64, 32, 24), 256, 0, stream>>>(w1, w3, w2, w1t, w3t, w2t);
  gemm1<<<dim3(I_DIM / 64, 32, E_NUM), 256, 0, stream>>>(xb, w1t, w3t, counts, list_tok, hbuf);
  gemm2<<<dim3(H_DIM / 128, 128, E_NUM), 256, 0, stream>>>(hbuf, w2t, counts, list_tok, list_w, partial);
  combine4<<<(T_TOK * H_DIM) / (256 * 4), 256, 0, stream>>>(partial, out);
}

// Round 4
// 349.656 us; speedup vs baseline: 1.2600x; 1.0516x over previous
//
#include <hip/hip_runtime.h>
#include <hip/hip_bf16.h>
#include <math.h>

typedef __attribute__((ext_vector_type(4))) float f32x4;
typedef __attribute__((ext_vector_type(8))) short bf16x8;

#define T_TOK 2048
#define H_DIM 1024
#define I_DIM 2048
#define E_NUM 8

// RNE float -> bf16
__device__ inline unsigned short f2bf(float f) {
  union { float f; unsigned int u; } v; v.f = f;
  unsigned int r = v.u + 0x7fffu + ((v.u >> 16) & 1u);
  return (unsigned short)(r >> 16);
}
__device__ inline unsigned int pack2(float a, float b) {
  return (unsigned int)f2bf(a) | ((unsigned int)f2bf(b) << 16);
}

// async global->LDS, 16 bytes per lane
__device__ inline void gld16(const void* g, void* l) {
  __builtin_amdgcn_global_load_lds((const __attribute__((address_space(1))) void*)g,
                                   (__attribute__((address_space(3))) void*)l, 16, 0, 0);
}

// ---------------- 64x64 fp32 [R][C] -> bf16 [C][R] tile transpose ----------------
// in: coalesced float4 rows (256B segments). LDS: bf16 tile [c][r] stride 66.
// out: 16B/lane stores, 8 lanes -> 128B contiguous segments.
__device__ inline void transpose_tile(const float* __restrict__ ip, unsigned short* __restrict__ op,
                                      int R, int C, int rt, int ct, char* smem)
{
  unsigned short (*tl)[66] = (unsigned short (*)[66])smem;
  int r0 = rt * 64, c0 = ct * 64;
  int tid = threadIdx.x;
  int rq = (tid >> 4) * 4;        // 4 consecutive rows per lane
  int c4 = (tid & 15) * 4;        // 4 consecutive cols per lane
  const float* base = ip + (size_t)(r0 + rq) * C + c0 + c4;
  float4 v0 = *(const float4*)(base);
  float4 v1 = *(const float4*)(base + C);
  float4 v2 = *(const float4*)(base + 2 * C);
  float4 v3 = *(const float4*)(base + 3 * C);
  const float* f0 = (const float*)&v0;
  const float* f1 = (const float*)&v1;
  const float* f2 = (const float*)&v2;
  const float* f3 = (const float*)&v3;
#pragma unroll
  for (int j = 0; j < 4; ++j) {
    *(unsigned int*)&tl[c4 + j][rq]     = pack2(f0[j], f1[j]);
    *(unsigned int*)&tl[c4 + j][rq + 2] = pack2(f2[j], f3[j]);
  }
  __syncthreads();
  int c = tid >> 3, r8 = (tid & 7) * 8;
#pragma unroll
  for (int it = 0; it < 2; ++it) {
    int cc = c + it * 32;
    uint4 o;
    o.x = *(const unsigned int*)&tl[cc][r8];
    o.y = *(const unsigned int*)&tl[cc][r8 + 2];
    o.z = *(const unsigned int*)&tl[cc][r8 + 4];
    o.w = *(const unsigned int*)&tl[cc][r8 + 6];
    *(uint4*)(op + (size_t)(c0 + cc) * R + r0 + r8) = o;
  }
}

// ---------------- kernel 1: gate (+x cast) fused with transpose of w1,w3 ----------------
// blocks [0,512): gate; [512, 512+8192): 64x64 tiles of w1 (m<8) / w3 (m>=8)
__global__ __launch_bounds__(256) void gate_t13(
    const float* __restrict__ x, const float* __restrict__ gw, const float* __restrict__ gb,
    int* __restrict__ rec_e, float* __restrict__ rec_w, unsigned short* __restrict__ xb,
    const float* __restrict__ w1, const float* __restrict__ w3,
    unsigned short* __restrict__ w1t, unsigned short* __restrict__ w3t)
{
  __shared__ __align__(16) char smem[64 * 66 * 2];
  int bx = blockIdx.x;
  if (bx >= 512) {
    int idx = bx - 512;
    int m = idx >> 9;          // 0..15
    int t9 = idx & 511;
    int rt = t9 & 15;          // R = H_DIM -> 16 tiles
    int ct = t9 >> 4;          // C = I_DIM -> 32 tiles
    const float* ip = (m < 8 ? w1 : w3) + (size_t)(m & 7) * ((size_t)H_DIM * I_DIM);
    unsigned short* op = (m < 8 ? w1t : w3t) + (size_t)(m & 7) * ((size_t)H_DIM * I_DIM);
    transpose_tile(ip, op, H_DIM, I_DIM, rt, ct, smem);
    return;
  }
  int wv = threadIdx.x >> 6, lane = threadIdx.x & 63;
  int t = bx * 4 + wv;
  const float* xr = x + (size_t)t * H_DIM;
  unsigned short* xo = xb + (size_t)t * H_DIM;
  float acc[8];
#pragma unroll
  for (int e = 0; e < 8; ++e) acc[e] = 0.f;
  for (int i = 0; i < H_DIM / 64; ++i) {
    int h = i * 64 + lane;
    float xv = xr[h];
    xo[h] = f2bf(xv);
    const float4* g = (const float4*)(gw + (size_t)h * 8);
    float4 g0 = g[0], g1 = g[1];
    acc[0] += xv * g0.x; acc[1] += xv * g0.y; acc[2] += xv * g0.z; acc[3] += xv * g0.w;
    acc[4] += xv * g1.x; acc[5] += xv * g1.y; acc[6] += xv * g1.z; acc[7] += xv * g1.w;
  }
#pragma unroll
  for (int s = 1; s < 64; s <<= 1) {
#pragma unroll
    for (int e = 0; e < 8; ++e) acc[e] += __shfl_xor(acc[e], s);
  }
  if (lane == 0) {
    float l[8];
#pragma unroll
    for (int e = 0; e < 8; ++e) l[e] = acc[e] + gb[e];
    int e0 = 0;
    for (int e = 1; e < 8; ++e) if (l[e] > l[e0]) e0 = e;
    int e1 = (e0 == 0) ? 1 : 0;
    for (int e = 0; e < 8; ++e) if (e != e0 && l[e] > l[e1]) e1 = e;
    float w0 = 1.f / (1.f + expf(l[e1] - l[e0]));
    rec_e[t * 2]     = e0; rec_e[t * 2 + 1] = e1;
    rec_w[t * 2]     = w0; rec_w[t * 2 + 1] = 1.f - w0;
  }
}

// ---------------- single-block routing ----------------
__global__ __launch_bounds__(256) void route_kernel(
    const int* __restrict__ rec_e, const float* __restrict__ rec_w,
    int* __restrict__ counts_g, int* __restrict__ list_tok, float* __restrict__ list_w)
{
  __shared__ int cnt[8], base[8], fill[8];
  int tid = threadIdx.x;
  if (tid < 8) { cnt[tid] = 0; fill[tid] = 0; }
  __syncthreads();
  int e_loc[16];
  int c_loc[8];
#pragma unroll
  for (int e = 0; e < 8; ++e) c_loc[e] = 0;
#pragma unroll
  for (int it = 0; it < 16; ++it) {
    e_loc[it] = rec_e[it * 256 + tid];
    c_loc[e_loc[it] & 7]++;
  }
#pragma unroll
  for (int e = 0; e < 8; ++e) if (c_loc[e]) atomicAdd(&cnt[e], c_loc[e]);
  __syncthreads();
  if (tid == 0) {
    int b = 0;
    for (int e = 0; e < 8; ++e) { base[e] = b; b += cnt[e]; }
  }
  if (tid < 8) counts_g[tid] = cnt[tid];
  __syncthreads();
#pragma unroll
  for (int it = 0; it < 16; ++it) {
    int i = it * 256 + tid;
    int e = e_loc[it] & 7;
    int pos = atomicAdd(&fill[e], 1);
    list_tok[base[e] + pos] = i;            // i = (t<<1)|k
    list_w[base[e] + pos]   = rec_w[i];
  }
}

// ---------------- kernel 3: gemm1 fused with transpose of w2 ----------------
// blocks [0,8192): gemm1 (e = bx>>10, y = (bx>>5)&31, ix = bx&31)
// blocks [8192, 8192+4096): 64x64 tiles of w2 (R=I_DIM, C=H_DIM)
__global__ __launch_bounds__(256) void gemm1_t2(
    const unsigned short* __restrict__ xb,
    const unsigned short* __restrict__ w1t,
    const unsigned short* __restrict__ w3t,
    const int* __restrict__ counts,
    const int* __restrict__ list_tok,
    unsigned short* __restrict__ hbuf,
    const float* __restrict__ w2,
    unsigned short* __restrict__ w2t)
{
  __shared__ __align__(16) char smem[16384];
  int bx = blockIdx.x;
  if (bx >= 8192) {
    int idx = bx - 8192;
    int e = idx >> 9;
    int t9 = idx & 511;
    int rt = t9 & 31;          // R = I_DIM -> 32 tiles
    int ct = t9 >> 5;          // C = H_DIM -> 16 tiles
    const float* ip = w2 + (size_t)e * ((size_t)H_DIM * I_DIM);
    unsigned short* op = w2t + (size_t)e * ((size_t)H_DIM * I_DIM);
    transpose_tile(ip, op, I_DIM, H_DIM, rt, ct, smem);
    return;
  }
  int e = bx >> 10;
  int y = (bx >> 5) & 31;
  int ix = bx & 31;
  int nbase = 0;
#pragma unroll
  for (int i = 0; i < 8; ++i) if (i < e) nbase += counts[i];
  int n_e = counts[e];
  int t0 = y * 128;
  if (t0 >= n_e) return;
  int i0 = ix * 64;

  unsigned short* As  = (unsigned short*)smem;           // 128*32 = 8KB
  unsigned short* B1s = (unsigned short*)(smem + 8192);  // 64*32 = 4KB
  unsigned short* B3s = (unsigned short*)(smem + 12288); // 64*32 = 4KB

  int tid = threadIdx.x;
  int r = tid >> 2;
  int seg = (tid & 3) * 8;

  int sr0 = t0 + r;       if (sr0 >= n_e) sr0 = n_e - 1;
  int sr1 = t0 + 64 + r;  if (sr1 >= n_e) sr1 = n_e - 1;
  int tok0 = list_tok[nbase + sr0] >> 1;
  int tok1 = list_tok[nbase + sr1] >> 1;
  const char* gA0 = (const char*)(xb + (size_t)tok0 * H_DIM + seg);
  const char* gA1 = (const char*)(xb + (size_t)tok1 * H_DIM + seg);
  const char* gB1 = (const char*)(w1t + ((size_t)e * I_DIM + i0 + r) * H_DIM + seg);
  const char* gB3 = (const char*)(w3t + ((size_t)e * I_DIM + i0 + r) * H_DIM + seg);

  char* lA0 = (char*)As + tid * 16;
  char* lA1 = (char*)As + 4096 + tid * 16;
  char* lB1 = (char*)B1s + tid * 16;
  char* lB3 = (char*)B3s + tid * 16;

  int w = tid >> 6, lane = tid & 63, lm = lane & 15, lq = lane >> 4;
  int wm = w & 1, wn = w >> 1;

  f32x4 acc1[4][2], acc3[4][2];
#pragma unroll
  for (int i = 0; i < 4; ++i)
#pragma unroll
    for (int j = 0; j < 2; ++j) { acc1[i][j] = (f32x4){0,0,0,0}; acc3[i][j] = (f32x4){0,0,0,0}; }

  for (int kb = 0; kb < H_DIM; kb += 32) {
    __syncthreads();
    gld16(gA0 + kb * 2, lA0);
    gld16(gA1 + kb * 2, lA1);
    gld16(gB1 + kb * 2, lB1);
    gld16(gB3 + kb * 2, lB3);
    __syncthreads();
    bf16x8 a[4], b1[2], b3[2];
#pragma unroll
    for (int i = 0; i < 4; ++i)
      a[i] = *(const bf16x8*)((const char*)As + 2 * ((wm * 64 + i * 16 + lm) * 32 + lq * 8));
#pragma unroll
    for (int j = 0; j < 2; ++j) {
      b1[j] = *(const bf16x8*)((const char*)B1s + 2 * ((wn * 32 + j * 16 + lm) * 32 + lq * 8));
      b3[j] = *(const bf16x8*)((const char*)B3s + 2 * ((wn * 32 + j * 16 + lm) * 32 + lq * 8));
    }
#pragma unroll
    for (int i = 0; i < 4; ++i)
#pragma unroll
      for (int j = 0; j < 2; ++j) {
        acc1[i][j] = __builtin_amdgcn_mfma_f32_16x16x32_bf16(a[i], b1[j], acc1[i][j], 0, 0, 0);
        acc3[i][j] = __builtin_amdgcn_mfma_f32_16x16x32_bf16(a[i], b3[j], acc3[i][j], 0, 0, 0);
      }
  }

#pragma unroll
  for (int i = 0; i < 4; ++i) {
#pragma unroll
    for (int rr = 0; rr < 4; ++rr) {
      int slot = t0 + wm * 64 + i * 16 + lq * 4 + rr;
      if (slot < n_e) {
#pragma unroll
        for (int j = 0; j < 2; ++j) {
          float g = acc1[i][j][rr], u = acc3[i][j][rr];
          float hv = (g / (1.f + __expf(-g))) * u;
          hbuf[(size_t)(nbase + slot) * I_DIM + i0 + wn * 32 + j * 16 + lm] = f2bf(hv);
        }
      }
    }
  }
}

// ---------------- GEMM2: 64 slots x 128 H, split-K=2, 4-plane partial ----------------
__global__ __launch_bounds__(256) void gemm2(
    const unsigned short* __restrict__ hbuf,
    const unsigned short* __restrict__ w2t,
    const int* __restrict__ counts,
    const int* __restrict__ list_tok,
    const float* __restrict__ list_w,
    float* __restrict__ partial)
{
  int e = blockIdx.z;
  int nbase = 0;
#pragma unroll
  for (int i = 0; i < 8; ++i) if (i < e) nbase += counts[i];
  int n_e = counts[e];
  int ts = blockIdx.y >> 1, kh = blockIdx.y & 1;
  int t0 = ts * 64;
  if (t0 >= n_e) return;
  int h0 = blockIdx.x * 128;
  int k0 = kh * (I_DIM / 2);

  __shared__ __align__(16) unsigned short As[64 * 32];    // 4KB
  __shared__ __align__(16) unsigned short Bs[128 * 32];   // 8KB

  int tid = threadIdx.x;
  int r = tid >> 2;
  int seg = (tid & 3) * 8;

  int sr = t0 + r; if (sr >= n_e) sr = n_e - 1;
  const char* gA  = (const char*)(hbuf + (size_t)(nbase + sr) * I_DIM + k0 + seg);
  const char* gB0 = (const char*)(w2t + ((size_t)e * H_DIM + h0 + r) * I_DIM + k0 + seg);
  const char* gB1 = (const char*)(w2t + ((size_t)e * H_DIM + h0 + 64 + r) * I_DIM + k0 + seg);

  char* lA  = (char*)As + tid * 16;
  char* lB0 = (char*)Bs + tid * 16;
  char* lB1 = (char*)Bs + 4096 + tid * 16;

  int w = tid >> 6, lane = tid & 63, lm = lane & 15, lq = lane >> 4;
  int wm = w & 1, wn = (w >> 1) * 64;

  f32x4 acc[2][4];
#pragma unroll
  for (int i = 0; i < 2; ++i)
#pragma unroll
    for (int j = 0; j < 4; ++j) acc[i][j] = (f32x4){0,0,0,0};

  for (int kb = 0; kb < I_DIM / 2; kb += 32) {
    __syncthreads();
    gld16(gA + kb * 2, lA);
    gld16(gB0 + kb * 2, lB0);
    gld16(gB1 + kb * 2, lB1);
    __syncthreads();
    bf16x8 a[2], b[4];
#pragma unroll
    for (int i = 0; i < 2; ++i)
      a[i] = *(const bf16x8*)((const char*)As + 2 * ((wm * 32 + i * 16 + lm) * 32 + lq * 8));
#pragma unroll
    for (int j = 0; j < 4; ++j)
      b[j] = *(const bf16x8*)((const char*)Bs + 2 * ((wn + j * 16 + lm) * 32 + lq * 8));
#pragma unroll
    for (int i = 0; i < 2; ++i)
#pragma unroll
      for (int j = 0; j < 4; ++j)
        acc[i][j] = __builtin_amdgcn_mfma_f32_16x16x32_bf16(a[i], b[j], acc[i][j], 0, 0, 0);
  }

  int entv[2][4]; float wtv[2][4];
#pragma unroll
  for (int i = 0; i < 2; ++i)
#pragma unroll
    for (int rr = 0; rr < 4; ++rr) {
      int slot = t0 + wm * 32 + i * 16 + lq * 4 + rr;
      if (slot < n_e) { entv[i][rr] = list_tok[nbase + slot]; wtv[i][rr] = list_w[nbase + slot]; }
      else entv[i][rr] = -1;
    }
#pragma unroll
  for (int i = 0; i < 2; ++i)
#pragma unroll
    for (int j = 0; j < 4; ++j)
#pragma unroll
      for (int rr = 0; rr < 4; ++rr) {
        if (entv[i][rr] >= 0) {
          int t = entv[i][rr] >> 1, kk = entv[i][rr] & 1;
          int plane = kh * 2 + kk;
          partial[((size_t)plane * T_TOK + t) * H_DIM + h0 + wn + j * 16 + lm] =
              acc[i][j][rr] * wtv[i][rr];
        }
      }
}

// ---------------- out = sum of 4 partial planes ----------------
__global__ __launch_bounds__(256) void combine4(const float* __restrict__ partial,
                                                float* __restrict__ out)
{
  const size_t P = (size_t)T_TOK * H_DIM;
  int i = (blockIdx.x * 256 + threadIdx.x) * 4;
  float4 a = *(const float4*)(partial + i);
  float4 b = *(const float4*)(partial + P + i);
  float4 c = *(const float4*)(partial + 2 * P + i);
  float4 d = *(const float4*)(partial + 3 * P + i);
  float4 o;
  o.x = a.x + b.x + c.x + d.x;
  o.y = a.y + b.y + c.y + d.y;
  o.z = a.z + b.z + c.z + d.z;
  o.w = a.w + b.w + c.w + d.w;
  *(float4*)(out + i) = o;
}

extern "C" void kernel_launch(void* const* d_in, const int* in_sizes, int n_in,
                              void* d_out, int out_size, void* d_ws, size_t ws_size,
                              hipStream_t stream) {
  const float* x  = (const float*)d_in[0];
  const float* gw = (const float*)d_in[1];
  const float* gb = (const float*)d_in[2];
  const float* w1 = (const float*)d_in[3];
  const float* w3 = (const float*)d_in[4];
  const float* w2 = (const float*)d_in[5];
  float* out = (float*)d_out;

  char* ws = (char*)d_ws;
  int*   counts   = (int*)(ws);            // 8 ints
  int*   rec_e    = (int*)(ws + 128);      // 4096 ints
  float* rec_w    = (float*)(ws + 16512);  // 4096 floats
  int*   list_tok = (int*)(ws + 32896);    // 4096 ints
  float* list_w   = (float*)(ws + 49280);  // 4096 floats
  const size_t MB = 1024ull * 1024ull;
  unsigned short* xb   = (unsigned short*)(ws + 1 * MB);    // 4 MB
  unsigned short* w1t  = (unsigned short*)(ws + 5 * MB);    // 32 MB  [E][I][H]
  float* partial       = (float*)(ws + 5 * MB);             // 32 MB  [4][T][H] (aliases w1t; dead after gemm1)
  unsigned short* w3t  = (unsigned short*)(ws + 37 * MB);   // 32 MB  [E][I][H]
  unsigned short* w2t  = (unsigned short*)(ws + 69 * MB);   // 32 MB  [E][H][I]
  unsigned short* hbuf = (unsigned short*)(ws + 101 * MB);  // 16 MB  [4096][I]

  gate_t13<<<512 + 8192, 256, 0, stream>>>(x, gw, gb, rec_e, rec_w, xb, w1, w3, w1t, w3t);
  route_kernel<<<1, 256, 0, stream>>>(rec_e, rec_w, counts, list_tok, list_w);
  gemm1_t2<<<8192 + 4096, 256, 0, stream>>>(xb, w1t, w3t, counts, list_tok, hbuf, w2, w2t);
  gemm2<<<dim3(H_DIM / 128, 128, E_NUM), 256, 0, stream>>>(hbuf, w2t, counts, list_tok, list_w, partial);
  combine4<<<(T_TOK * H_DIM) / (256 * 4), 256, 0, stream>>>(partial, out);
}

// Round 5
// 348.030 us; speedup vs baseline: 1.2659x; 1.0047x over previous
//
#include <hip/hip_runtime.h>
#include <hip/hip_bf16.h>
#include <math.h>

typedef __attribute__((ext_vector_type(4))) float f32x4;
typedef __attribute__((ext_vector_type(8))) short bf16x8;

#define T_TOK 2048
#define H_DIM 1024
#define I_DIM 2048
#define E_NUM 8

// RNE float -> bf16
__device__ inline unsigned short f2bf(float f) {
  union { float f; unsigned int u; } v; v.f = f;
  unsigned int r = v.u + 0x7fffu + ((v.u >> 16) & 1u);
  return (unsigned short)(r >> 16);
}
__device__ inline unsigned int pack2(float a, float b) {
  return (unsigned int)f2bf(a) | ((unsigned int)f2bf(b) << 16);
}

// async global->LDS, 16 bytes per lane
__device__ inline void gld16(const void* g, void* l) {
  __builtin_amdgcn_global_load_lds((const __attribute__((address_space(1))) void*)g,
                                   (__attribute__((address_space(3))) void*)l, 16, 0, 0);
}

// ---------------- 64x64 fp32 [R][C] -> bf16 [C][R] tile transpose ----------------
__device__ inline void transpose_tile(const float* __restrict__ ip, unsigned short* __restrict__ op,
                                      int R, int C, int rt, int ct, char* smem)
{
  unsigned short (*tl)[66] = (unsigned short (*)[66])smem;
  int r0 = rt * 64, c0 = ct * 64;
  int tid = threadIdx.x;
  int rq = (tid >> 4) * 4;
  int c4 = (tid & 15) * 4;
  const float* base = ip + (size_t)(r0 + rq) * C + c0 + c4;
  float4 v0 = *(const float4*)(base);
  float4 v1 = *(const float4*)(base + C);
  float4 v2 = *(const float4*)(base + 2 * C);
  float4 v3 = *(const float4*)(base + 3 * C);
  const float* f0 = (const float*)&v0;
  const float* f1 = (const float*)&v1;
  const float* f2 = (const float*)&v2;
  const float* f3 = (const float*)&v3;
#pragma unroll
  for (int j = 0; j < 4; ++j) {
    *(unsigned int*)&tl[c4 + j][rq]     = pack2(f0[j], f1[j]);
    *(unsigned int*)&tl[c4 + j][rq + 2] = pack2(f2[j], f3[j]);
  }
  __syncthreads();
  int c = tid >> 3, r8 = (tid & 7) * 8;
#pragma unroll
  for (int it = 0; it < 2; ++it) {
    int cc = c + it * 32;
    uint4 o;
    o.x = *(const unsigned int*)&tl[cc][r8];
    o.y = *(const unsigned int*)&tl[cc][r8 + 2];
    o.z = *(const unsigned int*)&tl[cc][r8 + 4];
    o.w = *(const unsigned int*)&tl[cc][r8 + 6];
    *(uint4*)(op + (size_t)(c0 + cc) * R + r0 + r8) = o;
  }
}

// ---------------- kernel 1: gate (+x cast) fused with transpose of w1,w3 ----------------
__global__ __launch_bounds__(256) void gate_t13(
    const float* __restrict__ x, const float* __restrict__ gw, const float* __restrict__ gb,
    int* __restrict__ rec_e, float* __restrict__ rec_w, unsigned short* __restrict__ xb,
    const float* __restrict__ w1, const float* __restrict__ w3,
    unsigned short* __restrict__ w1t, unsigned short* __restrict__ w3t)
{
  __shared__ __align__(16) char smem[64 * 66 * 2];
  int bx = blockIdx.x;
  if (bx >= 512) {
    int idx = bx - 512;
    int m = idx >> 9;          // 0..15
    int t9 = idx & 511;
    int rt = t9 & 15;          // R = H_DIM -> 16 tiles
    int ct = t9 >> 4;          // C = I_DIM -> 32 tiles
    const float* ip = (m < 8 ? w1 : w3) + (size_t)(m & 7) * ((size_t)H_DIM * I_DIM);
    unsigned short* op = (m < 8 ? w1t : w3t) + (size_t)(m & 7) * ((size_t)H_DIM * I_DIM);
    transpose_tile(ip, op, H_DIM, I_DIM, rt, ct, smem);
    return;
  }
  int wv = threadIdx.x >> 6, lane = threadIdx.x & 63;
  int t = bx * 4 + wv;
  const float* xr = x + (size_t)t * H_DIM;
  unsigned short* xo = xb + (size_t)t * H_DIM;
  float acc[8];
#pragma unroll
  for (int e = 0; e < 8; ++e) acc[e] = 0.f;
  for (int i = 0; i < H_DIM / 64; ++i) {
    int h = i * 64 + lane;
    float xv = xr[h];
    xo[h] = f2bf(xv);
    const float4* g = (const float4*)(gw + (size_t)h * 8);
    float4 g0 = g[0], g1 = g[1];
    acc[0] += xv * g0.x; acc[1] += xv * g0.y; acc[2] += xv * g0.z; acc[3] += xv * g0.w;
    acc[4] += xv * g1.x; acc[5] += xv * g1.y; acc[6] += xv * g1.z; acc[7] += xv * g1.w;
  }
#pragma unroll
  for (int s = 1; s < 64; s <<= 1) {
#pragma unroll
    for (int e = 0; e < 8; ++e) acc[e] += __shfl_xor(acc[e], s);
  }
  if (lane == 0) {
    float l[8];
#pragma unroll
    for (int e = 0; e < 8; ++e) l[e] = acc[e] + gb[e];
    int e0 = 0;
    for (int e = 1; e < 8; ++e) if (l[e] > l[e0]) e0 = e;
    int e1 = (e0 == 0) ? 1 : 0;
    for (int e = 0; e < 8; ++e) if (e != e0 && l[e] > l[e1]) e1 = e;
    float w0 = 1.f / (1.f + expf(l[e1] - l[e0]));
    rec_e[t * 2]     = e0; rec_e[t * 2 + 1] = e1;
    rec_w[t * 2]     = w0; rec_w[t * 2 + 1] = 1.f - w0;
  }
}

// ---------------- routing: 8 blocks, one per expert ----------------
__global__ __launch_bounds__(256) void route8(
    const int* __restrict__ rec_e, const float* __restrict__ rec_w,
    int* __restrict__ counts_g, int* __restrict__ list_tok, float* __restrict__ list_w)
{
  __shared__ int cnt[8];
  __shared__ int fill;
  int e = blockIdx.x;
  int tid = threadIdx.x;
  if (tid < 8) cnt[tid] = 0;
  if (tid == 0) fill = 0;
  __syncthreads();
  int e_loc[16];
  int c_loc[8];
#pragma unroll
  for (int k = 0; k < 8; ++k) c_loc[k] = 0;
#pragma unroll
  for (int it = 0; it < 16; ++it) {
    e_loc[it] = rec_e[it * 256 + tid] & 7;
    c_loc[e_loc[it]]++;
  }
#pragma unroll
  for (int k = 0; k < 8; ++k) if (c_loc[k]) atomicAdd(&cnt[k], c_loc[k]);
  __syncthreads();
  if (e == 0 && tid < 8) counts_g[tid] = cnt[tid];
  int base = 0;
#pragma unroll
  for (int k = 0; k < 8; ++k) if (k < e) base += cnt[k];
#pragma unroll
  for (int it = 0; it < 16; ++it) {
    if (e_loc[it] == e) {
      int i = it * 256 + tid;
      int pos = atomicAdd(&fill, 1);
      list_tok[base + pos] = i;            // i = (t<<1)|k
      list_w[base + pos]   = rec_w[i];
    }
  }
}

// ---------------- kernel 3: gemm1 (128x128, dual) fused with transpose of w2 ----------------
// blocks [0,4096): gemm1 (e = bx>>9, y = (bx>>4)&31, ix = bx&15)
// blocks [4096, 8192): 64x64 tiles of w2 (R=I_DIM, C=H_DIM)
__global__ __launch_bounds__(256, 2) void gemm1_t2(
    const unsigned short* __restrict__ xb,
    const unsigned short* __restrict__ w1t,
    const unsigned short* __restrict__ w3t,
    const int* __restrict__ counts,
    const int* __restrict__ list_tok,
    unsigned short* __restrict__ hbuf,
    const float* __restrict__ w2,
    unsigned short* __restrict__ w2t)
{
  __shared__ __align__(16) char smem[24576];
  int bx = blockIdx.x;
  if (bx >= 4096) {
    int idx = bx - 4096;
    int e = idx >> 9;
    int t9 = idx & 511;
    int rt = t9 & 31;          // R = I_DIM -> 32 tiles
    int ct = t9 >> 5;          // C = H_DIM -> 16 tiles
    const float* ip = w2 + (size_t)e * ((size_t)H_DIM * I_DIM);
    unsigned short* op = w2t + (size_t)e * ((size_t)H_DIM * I_DIM);
    transpose_tile(ip, op, I_DIM, H_DIM, rt, ct, smem);
    return;
  }
  int e = bx >> 9;
  int y = (bx >> 4) & 31;
  int ix = bx & 15;
  int nbase = 0;
#pragma unroll
  for (int i = 0; i < 8; ++i) if (i < e) nbase += counts[i];
  int n_e = counts[e];
  int t0 = y * 128;
  if (t0 >= n_e) return;
  int i0 = ix * 128;

  unsigned short* As  = (unsigned short*)smem;            // 128*32 = 8KB
  unsigned short* B1s = (unsigned short*)(smem + 8192);   // 128*32 = 8KB
  unsigned short* B3s = (unsigned short*)(smem + 16384);  // 128*32 = 8KB

  int tid = threadIdx.x;
  int r4 = tid >> 2;           // 0..63
  int seg = (tid & 3) * 8;     // bf16 elems within 32-k row

  int sr0 = t0 + r4;       if (sr0 >= n_e) sr0 = n_e - 1;
  int sr1 = t0 + 64 + r4;  if (sr1 >= n_e) sr1 = n_e - 1;
  int tok0 = list_tok[nbase + sr0] >> 1;
  int tok1 = list_tok[nbase + sr1] >> 1;
  const char* gA0 = (const char*)(xb + (size_t)tok0 * H_DIM + seg);
  const char* gA1 = (const char*)(xb + (size_t)tok1 * H_DIM + seg);
  const char* gB1a = (const char*)(w1t + ((size_t)e * I_DIM + i0 + r4) * H_DIM + seg);
  const char* gB1b = (const char*)(w1t + ((size_t)e * I_DIM + i0 + 64 + r4) * H_DIM + seg);
  const char* gB3a = (const char*)(w3t + ((size_t)e * I_DIM + i0 + r4) * H_DIM + seg);
  const char* gB3b = (const char*)(w3t + ((size_t)e * I_DIM + i0 + 64 + r4) * H_DIM + seg);

  char* lA0  = (char*)As + tid * 16;
  char* lA1  = (char*)As + 4096 + tid * 16;
  char* lB1a = (char*)B1s + tid * 16;
  char* lB1b = (char*)B1s + 4096 + tid * 16;
  char* lB3a = (char*)B3s + tid * 16;
  char* lB3b = (char*)B3s + 4096 + tid * 16;

  int w = tid >> 6, lane = tid & 63, lm = lane & 15, lq = lane >> 4;
  int wm = w & 1, wn = w >> 1;   // m-off wm*64, n-off wn*64

  f32x4 acc1[4][4], acc3[4][4];
#pragma unroll
  for (int i = 0; i < 4; ++i)
#pragma unroll
    for (int j = 0; j < 4; ++j) { acc1[i][j] = (f32x4){0,0,0,0}; acc3[i][j] = (f32x4){0,0,0,0}; }

  for (int kb = 0; kb < H_DIM; kb += 32) {
    __syncthreads();
    gld16(gA0 + kb * 2, lA0);
    gld16(gA1 + kb * 2, lA1);
    gld16(gB1a + kb * 2, lB1a);
    gld16(gB1b + kb * 2, lB1b);
    gld16(gB3a + kb * 2, lB3a);
    gld16(gB3b + kb * 2, lB3b);
    __syncthreads();
    bf16x8 a[4], b1[4], b3[4];
#pragma unroll
    for (int i = 0; i < 4; ++i)
      a[i] = *(const bf16x8*)((const char*)As + 2 * ((wm * 64 + i * 16 + lm) * 32 + lq * 8));
#pragma unroll
    for (int j = 0; j < 4; ++j) {
      b1[j] = *(const bf16x8*)((const char*)B1s + 2 * ((wn * 64 + j * 16 + lm) * 32 + lq * 8));
      b3[j] = *(const bf16x8*)((const char*)B3s + 2 * ((wn * 64 + j * 16 + lm) * 32 + lq * 8));
    }
#pragma unroll
    for (int i = 0; i < 4; ++i)
#pragma unroll
      for (int j = 0; j < 4; ++j) {
        acc1[i][j] = __builtin_amdgcn_mfma_f32_16x16x32_bf16(a[i], b1[j], acc1[i][j], 0, 0, 0);
        acc3[i][j] = __builtin_amdgcn_mfma_f32_16x16x32_bf16(a[i], b3[j], acc3[i][j], 0, 0, 0);
      }
  }

#pragma unroll
  for (int i = 0; i < 4; ++i) {
#pragma unroll
    for (int rr = 0; rr < 4; ++rr) {
      int slot = t0 + wm * 64 + i * 16 + lq * 4 + rr;
      if (slot < n_e) {
        unsigned short* orow = hbuf + (size_t)(nbase + slot) * I_DIM + i0 + wn * 64 + lm;
#pragma unroll
        for (int j = 0; j < 4; ++j) {
          float g = acc1[i][j][rr], u = acc3[i][j][rr];
          float hv = (g / (1.f + __expf(-g))) * u;
          orow[j * 16] = f2bf(hv);
        }
      }
    }
  }
}

// ---------------- GEMM2: 64 slots x 128 H, split-K=4, 8-plane partial ----------------
__global__ __launch_bounds__(256) void gemm2(
    const unsigned short* __restrict__ hbuf,
    const unsigned short* __restrict__ w2t,
    const int* __restrict__ counts,
    const int* __restrict__ list_tok,
    const float* __restrict__ list_w,
    float* __restrict__ partial)
{
  int e = blockIdx.z;
  int nbase = 0;
#pragma unroll
  for (int i = 0; i < 8; ++i) if (i < e) nbase += counts[i];
  int n_e = counts[e];
  int ts = blockIdx.y >> 2, kh = blockIdx.y & 3;
  int t0 = ts * 64;
  if (t0 >= n_e) return;
  int h0 = blockIdx.x * 128;
  int k0 = kh * (I_DIM / 4);

  __shared__ __align__(16) unsigned short As[64 * 32];    // 4KB
  __shared__ __align__(16) unsigned short Bs[128 * 32];   // 8KB

  int tid = threadIdx.x;
  int r = tid >> 2;
  int seg = (tid & 3) * 8;

  int sr = t0 + r; if (sr >= n_e) sr = n_e - 1;
  const char* gA  = (const char*)(hbuf + (size_t)(nbase + sr) * I_DIM + k0 + seg);
  const char* gB0 = (const char*)(w2t + ((size_t)e * H_DIM + h0 + r) * I_DIM + k0 + seg);
  const char* gB1 = (const char*)(w2t + ((size_t)e * H_DIM + h0 + 64 + r) * I_DIM + k0 + seg);

  char* lA  = (char*)As + tid * 16;
  char* lB0 = (char*)Bs + tid * 16;
  char* lB1 = (char*)Bs + 4096 + tid * 16;

  int w = tid >> 6, lane = tid & 63, lm = lane & 15, lq = lane >> 4;
  int wm = w & 1, wn = (w >> 1) * 64;

  f32x4 acc[2][4];
#pragma unroll
  for (int i = 0; i < 2; ++i)
#pragma unroll
    for (int j = 0; j < 4; ++j) acc[i][j] = (f32x4){0,0,0,0};

  for (int kb = 0; kb < I_DIM / 4; kb += 32) {
    __syncthreads();
    gld16(gA + kb * 2, lA);
    gld16(gB0 + kb * 2, lB0);
    gld16(gB1 + kb * 2, lB1);
    __syncthreads();
    bf16x8 a[2], b[4];
#pragma unroll
    for (int i = 0; i < 2; ++i)
      a[i] = *(const bf16x8*)((const char*)As + 2 * ((wm * 32 + i * 16 + lm) * 32 + lq * 8));
#pragma unroll
    for (int j = 0; j < 4; ++j)
      b[j] = *(const bf16x8*)((const char*)Bs + 2 * ((wn + j * 16 + lm) * 32 + lq * 8));
#pragma unroll
    for (int i = 0; i < 2; ++i)
#pragma unroll
      for (int j = 0; j < 4; ++j)
        acc[i][j] = __builtin_amdgcn_mfma_f32_16x16x32_bf16(a[i], b[j], acc[i][j], 0, 0, 0);
  }

  int entv[2][4]; float wtv[2][4];
#pragma unroll
  for (int i = 0; i < 2; ++i)
#pragma unroll
    for (int rr = 0; rr < 4; ++rr) {
      int slot = t0 + wm * 32 + i * 16 + lq * 4 + rr;
      if (slot < n_e) { entv[i][rr] = list_tok[nbase + slot]; wtv[i][rr] = list_w[nbase + slot]; }
      else entv[i][rr] = -1;
    }
#pragma unroll
  for (int i = 0; i < 2; ++i)
#pragma unroll
    for (int j = 0; j < 4; ++j)
#pragma unroll
      for (int rr = 0; rr < 4; ++rr) {
        if (entv[i][rr] >= 0) {
          int t = entv[i][rr] >> 1, kk = entv[i][rr] & 1;
          int plane = kh * 2 + kk;
          partial[((size_t)plane * T_TOK + t) * H_DIM + h0 + wn + j * 16 + lm] =
              acc[i][j][rr] * wtv[i][rr];
        }
      }
}

// ---------------- out = sum of 8 partial planes ----------------
__global__ __launch_bounds__(256) void combine8(const float* __restrict__ partial,
                                                float* __restrict__ out)
{
  const size_t P = (size_t)T_TOK * H_DIM;
  size_t i = (size_t)(blockIdx.x * 256 + threadIdx.x) * 4;
  float4 s = *(const float4*)(partial + i);
#pragma unroll
  for (int p = 1; p < 8; ++p) {
    float4 v = *(const float4*)(partial + p * P + i);
    s.x += v.x; s.y += v.y; s.z += v.z; s.w += v.w;
  }
  *(float4*)(out + i) = s;
}

extern "C" void kernel_launch(void* const* d_in, const int* in_sizes, int n_in,
                              void* d_out, int out_size, void* d_ws, size_t ws_size,
                              hipStream_t stream) {
  const float* x  = (const float*)d_in[0];
  const float* gw = (const float*)d_in[1];
  const float* gb = (const float*)d_in[2];
  const float* w1 = (const float*)d_in[3];
  const float* w3 = (const float*)d_in[4];
  const float* w2 = (const float*)d_in[5];
  float* out = (float*)d_out;

  char* ws = (char*)d_ws;
  int*   counts   = (int*)(ws);            // 8 ints
  int*   rec_e    = (int*)(ws + 128);      // 4096 ints
  float* rec_w    = (float*)(ws + 16512);  // 4096 floats
  int*   list_tok = (int*)(ws + 32896);    // 4096 ints
  float* list_w   = (float*)(ws + 49280);  // 4096 floats
  const size_t MB = 1024ull * 1024ull;
  unsigned short* xb   = (unsigned short*)(ws + 1 * MB);    // 4 MB
  unsigned short* w1t  = (unsigned short*)(ws + 5 * MB);    // 32 MB  [E][I][H]
  float* partial       = (float*)(ws + 5 * MB);             // 64 MB  [8][T][H] (aliases w1t+w3t; dead after gemm1_t2)
  unsigned short* w3t  = (unsigned short*)(ws + 37 * MB);   // 32 MB  [E][I][H]
  unsigned short* w2t  = (unsigned short*)(ws + 69 * MB);   // 32 MB  [E][H][I]
  unsigned short* hbuf = (unsigned short*)(ws + 101 * MB);  // 16 MB  [4096][I]

  gate_t13<<<512 + 8192, 256, 0, stream>>>(x, gw, gb, rec_e, rec_w, xb, w1, w3, w1t, w3t);
  route8<<<8, 256, 0, stream>>>(rec_e, rec_w, counts, list_tok, list_w);
  gemm1_t2<<<4096 + 4096, 256, 0, stream>>>(xb, w1t, w3t, counts, list_tok, hbuf, w2, w2t);
  gemm2<<<dim3(H_DIM / 128, 256, E_NUM), 256, 0, stream>>>(hbuf, w2t, counts, list_tok, list_w, partial);
  combine8<<<(T_TOK * H_DIM) / (256 * 4), 256, 0, stream>>>(partial, out);
}

// Round 6
// 336.598 us; speedup vs baseline: 1.3089x; 1.0340x over previous
//
#include <hip/hip_runtime.h>
#include <hip/hip_bf16.h>
#include <math.h>

typedef __attribute__((ext_vector_type(4))) float f32x4;
typedef __attribute__((ext_vector_type(8))) short bf16x8;

#define T_TOK 2048
#define H_DIM 1024
#define I_DIM 2048
#define E_NUM 8

// RNE float -> bf16
__device__ inline unsigned short f2bf(float f) {
  union { float f; unsigned int u; } v; v.f = f;
  unsigned int r = v.u + 0x7fffu + ((v.u >> 16) & 1u);
  return (unsigned short)(r >> 16);
}
__device__ inline unsigned int pack2(float a, float b) {
  return (unsigned int)f2bf(a) | ((unsigned int)f2bf(b) << 16);
}

// async global->LDS, 16 bytes per lane
__device__ inline void gld16(const void* g, void* l) {
  __builtin_amdgcn_global_load_lds((const __attribute__((address_space(1))) void*)g,
                                   (__attribute__((address_space(3))) void*)l, 16, 0, 0);
}

// ---------------- paired 64x64 fp32 [R][C] -> bf16 [C][R] transpose ----------------
// One block handles rows [rp*128, rp*128+128) x cols [ct*64, ct*64+64).
// 8 float4 loads issued up-front (MLP), per-column 2x128B contiguous stores.
__device__ inline void transpose_pair(const float* __restrict__ ip, unsigned short* __restrict__ op,
                                      int R, int C, int rp, int ct, char* smem)
{
  unsigned short (*tl)[66] = (unsigned short (*)[66])smem;   // [2*64 cols][64 rows + pad2]
  int r0 = rp * 128, c0 = ct * 64;
  int tid = threadIdx.x;
  int rq = (tid >> 4) * 4;        // 4 consecutive rows within 64-row tile
  int c4 = (tid & 15) * 4;        // 4 consecutive cols
  const float* b0 = ip + (size_t)(r0 + rq) * C + c0 + c4;
  const float* b1 = b0 + (size_t)64 * C;
  float4 v[8];
  v[0] = *(const float4*)(b0);
  v[1] = *(const float4*)(b0 + C);
  v[2] = *(const float4*)(b0 + 2 * C);
  v[3] = *(const float4*)(b0 + 3 * C);
  v[4] = *(const float4*)(b1);
  v[5] = *(const float4*)(b1 + C);
  v[6] = *(const float4*)(b1 + 2 * C);
  v[7] = *(const float4*)(b1 + 3 * C);
  const float* f = (const float*)v;
#pragma unroll
  for (int j = 0; j < 4; ++j) {
    *(unsigned int*)&tl[c4 + j][rq]          = pack2(f[0 * 4 + j], f[1 * 4 + j]);
    *(unsigned int*)&tl[c4 + j][rq + 2]      = pack2(f[2 * 4 + j], f[3 * 4 + j]);
    *(unsigned int*)&tl[64 + c4 + j][rq]     = pack2(f[4 * 4 + j], f[5 * 4 + j]);
    *(unsigned int*)&tl[64 + c4 + j][rq + 2] = pack2(f[6 * 4 + j], f[7 * 4 + j]);
  }
  __syncthreads();
  int c = tid >> 3, r8 = (tid & 7) * 8;
#pragma unroll
  for (int it = 0; it < 2; ++it) {
    int cc = c + it * 32;
#pragma unroll
    for (int p = 0; p < 2; ++p) {
      uint4 o;
      o.x = *(const unsigned int*)&tl[p * 64 + cc][r8];
      o.y = *(const unsigned int*)&tl[p * 64 + cc][r8 + 2];
      o.z = *(const unsigned int*)&tl[p * 64 + cc][r8 + 4];
      o.w = *(const unsigned int*)&tl[p * 64 + cc][r8 + 6];
      *(uint4*)(op + (size_t)(c0 + cc) * R + r0 + p * 64 + r8) = o;
    }
  }
}

// ---------------- kernel 1: gate (+x cast) fused with transpose of w1,w3 ----------------
// blocks [0,512): gate; [512, 512+4096): 128x64 tile-pairs of w1 (m<8) / w3 (m>=8)
__global__ __launch_bounds__(256) void gate_t13(
    const float* __restrict__ x, const float* __restrict__ gw, const float* __restrict__ gb,
    int* __restrict__ rec_e, float* __restrict__ rec_w, unsigned short* __restrict__ xb,
    const float* __restrict__ w1, const float* __restrict__ w3,
    unsigned short* __restrict__ w1t, unsigned short* __restrict__ w3t)
{
  __shared__ __align__(16) char smem[128 * 66 * 2];
  int bx = blockIdx.x;
  if (bx >= 512) {
    int idx = bx - 512;
    int m = idx >> 8;          // 0..15
    int t8 = idx & 255;
    int rp = t8 & 7;           // R = H_DIM -> 8 row-pairs
    int ct = t8 >> 3;          // C = I_DIM -> 32 col tiles
    const float* ip = (m < 8 ? w1 : w3) + (size_t)(m & 7) * ((size_t)H_DIM * I_DIM);
    unsigned short* op = (m < 8 ? w1t : w3t) + (size_t)(m & 7) * ((size_t)H_DIM * I_DIM);
    transpose_pair(ip, op, H_DIM, I_DIM, rp, ct, smem);
    return;
  }
  int wv = threadIdx.x >> 6, lane = threadIdx.x & 63;
  int t = bx * 4 + wv;
  const float* xr = x + (size_t)t * H_DIM;
  unsigned short* xo = xb + (size_t)t * H_DIM;
  float acc[8];
#pragma unroll
  for (int e = 0; e < 8; ++e) acc[e] = 0.f;
  for (int i = 0; i < H_DIM / 64; ++i) {
    int h = i * 64 + lane;
    float xv = xr[h];
    xo[h] = f2bf(xv);
    const float4* g = (const float4*)(gw + (size_t)h * 8);
    float4 g0 = g[0], g1 = g[1];
    acc[0] += xv * g0.x; acc[1] += xv * g0.y; acc[2] += xv * g0.z; acc[3] += xv * g0.w;
    acc[4] += xv * g1.x; acc[5] += xv * g1.y; acc[6] += xv * g1.z; acc[7] += xv * g1.w;
  }
#pragma unroll
  for (int s = 1; s < 64; s <<= 1) {
#pragma unroll
    for (int e = 0; e < 8; ++e) acc[e] += __shfl_xor(acc[e], s);
  }
  if (lane == 0) {
    float l[8];
#pragma unroll
    for (int e = 0; e < 8; ++e) l[e] = acc[e] + gb[e];
    int e0 = 0;
    for (int e = 1; e < 8; ++e) if (l[e] > l[e0]) e0 = e;
    int e1 = (e0 == 0) ? 1 : 0;
    for (int e = 0; e < 8; ++e) if (e != e0 && l[e] > l[e1]) e1 = e;
    float w0 = 1.f / (1.f + expf(l[e1] - l[e0]));
    rec_e[t * 2]     = e0; rec_e[t * 2 + 1] = e1;
    rec_w[t * 2]     = w0; rec_w[t * 2 + 1] = 1.f - w0;
  }
}

// ---------------- routing: 8 blocks, one per expert ----------------
__global__ __launch_bounds__(256) void route8(
    const int* __restrict__ rec_e, const float* __restrict__ rec_w,
    int* __restrict__ counts_g, int* __restrict__ list_tok, float* __restrict__ list_w)
{
  __shared__ int cnt[8];
  __shared__ int fill;
  int e = blockIdx.x;
  int tid = threadIdx.x;
  if (tid < 8) cnt[tid] = 0;
  if (tid == 0) fill = 0;
  __syncthreads();
  int e_loc[16];
  int c_loc[8];
#pragma unroll
  for (int k = 0; k < 8; ++k) c_loc[k] = 0;
#pragma unroll
  for (int it = 0; it < 16; ++it) {
    e_loc[it] = rec_e[it * 256 + tid] & 7;
    c_loc[e_loc[it]]++;
  }
#pragma unroll
  for (int k = 0; k < 8; ++k) if (c_loc[k]) atomicAdd(&cnt[k], c_loc[k]);
  __syncthreads();
  if (e == 0 && tid < 8) counts_g[tid] = cnt[tid];
  int base = 0;
#pragma unroll
  for (int k = 0; k < 8; ++k) if (k < e) base += cnt[k];
#pragma unroll
  for (int it = 0; it < 16; ++it) {
    if (e_loc[it] == e) {
      int i = it * 256 + tid;
      int pos = atomicAdd(&fill, 1);
      list_tok[base + pos] = i;            // i = (t<<1)|k
      list_w[base + pos]   = rec_w[i];
    }
  }
}

// ---------------- kernel 3: gemm1 (128x128, dual, BK=64) fused with transpose of w2 ----------------
// blocks [0,4096): gemm1 (e = bx>>9, y = (bx>>4)&31, ix = bx&15)
// blocks [4096, 4096+2048): 128x64 tile-pairs of w2 (R=I_DIM, C=H_DIM)
__global__ __launch_bounds__(256, 2) void gemm1_t2(
    const unsigned short* __restrict__ xb,
    const unsigned short* __restrict__ w1t,
    const unsigned short* __restrict__ w3t,
    const int* __restrict__ counts,
    const int* __restrict__ list_tok,
    unsigned short* __restrict__ hbuf,
    const float* __restrict__ w2,
    unsigned short* __restrict__ w2t)
{
  __shared__ __align__(16) char smem[49152];
  int bx = blockIdx.x;
  if (bx >= 4096) {
    int idx = bx - 4096;
    int e = idx >> 8;          // 0..7
    int t8 = idx & 255;
    int rp = t8 & 15;          // R = I_DIM -> 16 row-pairs
    int ct = t8 >> 4;          // C = H_DIM -> 16 col tiles
    const float* ip = w2 + (size_t)e * ((size_t)H_DIM * I_DIM);
    unsigned short* op = w2t + (size_t)e * ((size_t)H_DIM * I_DIM);
    transpose_pair(ip, op, I_DIM, H_DIM, rp, ct, smem);
    return;
  }
  int e = bx >> 9;
  int y = (bx >> 4) & 31;
  int ix = bx & 15;
  int nbase = 0;
#pragma unroll
  for (int i = 0; i < 8; ++i) if (i < e) nbase += counts[i];
  int n_e = counts[e];
  int t0 = y * 128;
  if (t0 >= n_e) return;
  int i0 = ix * 128;

  // LDS: As 2 panels (128 rows x 32 k, 64B rows) = 16KB; B1s 16KB; B3s 16KB
  char* As  = smem;
  char* B1s = smem + 16384;
  char* B3s = smem + 32768;

  int tid = threadIdx.x;
  int r2 = tid >> 2;           // 0..63 (row within 64-row half)
  int seg = (tid & 3) * 8;     // bf16 elems within 32-k panel row

  int sr0 = t0 + r2;       if (sr0 >= n_e) sr0 = n_e - 1;
  int sr1 = t0 + 64 + r2;  if (sr1 >= n_e) sr1 = n_e - 1;
  int tok0 = list_tok[nbase + sr0] >> 1;
  int tok1 = list_tok[nbase + sr1] >> 1;
  const char* gA0 = (const char*)(xb + (size_t)tok0 * H_DIM + seg);
  const char* gA1 = (const char*)(xb + (size_t)tok1 * H_DIM + seg);
  const char* gB1a = (const char*)(w1t + ((size_t)e * I_DIM + i0 + r2) * H_DIM + seg);
  const char* gB1b = (const char*)(w1t + ((size_t)e * I_DIM + i0 + 64 + r2) * H_DIM + seg);
  const char* gB3a = (const char*)(w3t + ((size_t)e * I_DIM + i0 + r2) * H_DIM + seg);
  const char* gB3b = (const char*)(w3t + ((size_t)e * I_DIM + i0 + 64 + r2) * H_DIM + seg);

  // LDS staging destinations: sub-load c -> buf + c*4096 + tid*16
  int w = tid >> 6, lane = tid & 63, lm = lane & 15, lq = lane >> 4;
  int wm = w & 1, wn = w >> 1;   // m-off wm*64, n-off wn*64

  f32x4 acc1[4][4], acc3[4][4];
#pragma unroll
  for (int i = 0; i < 4; ++i)
#pragma unroll
    for (int j = 0; j < 4; ++j) { acc1[i][j] = (f32x4){0,0,0,0}; acc3[i][j] = (f32x4){0,0,0,0}; }

  for (int kb = 0; kb < H_DIM; kb += 64) {
    __syncthreads();
    // panel 0: k = kb..kb+31 ; panel 1: k = kb+32..kb+63 (+64 bytes)
    gld16(gA0 + kb * 2,       As + tid * 16);
    gld16(gA1 + kb * 2,       As + 4096 + tid * 16);
    gld16(gA0 + kb * 2 + 64,  As + 8192 + tid * 16);
    gld16(gA1 + kb * 2 + 64,  As + 12288 + tid * 16);
    gld16(gB1a + kb * 2,      B1s + tid * 16);
    gld16(gB1b + kb * 2,      B1s + 4096 + tid * 16);
    gld16(gB1a + kb * 2 + 64, B1s + 8192 + tid * 16);
    gld16(gB1b + kb * 2 + 64, B1s + 12288 + tid * 16);
    gld16(gB3a + kb * 2,      B3s + tid * 16);
    gld16(gB3b + kb * 2,      B3s + 4096 + tid * 16);
    gld16(gB3a + kb * 2 + 64, B3s + 8192 + tid * 16);
    gld16(gB3b + kb * 2 + 64, B3s + 12288 + tid * 16);
    __syncthreads();
#pragma unroll
    for (int s = 0; s < 2; ++s) {
      bf16x8 a[4], b1[4], b3[4];
#pragma unroll
      for (int i = 0; i < 4; ++i)
        a[i] = *(const bf16x8*)(As + s * 8192 + ((wm * 64 + i * 16 + lm) * 32 + lq * 8) * 2);
#pragma unroll
      for (int j = 0; j < 4; ++j) {
        b1[j] = *(const bf16x8*)(B1s + s * 8192 + ((wn * 64 + j * 16 + lm) * 32 + lq * 8) * 2);
        b3[j] = *(const bf16x8*)(B3s + s * 8192 + ((wn * 64 + j * 16 + lm) * 32 + lq * 8) * 2);
      }
#pragma unroll
      for (int i = 0; i < 4; ++i)
#pragma unroll
        for (int j = 0; j < 4; ++j) {
          acc1[i][j] = __builtin_amdgcn_mfma_f32_16x16x32_bf16(a[i], b1[j], acc1[i][j], 0, 0, 0);
          acc3[i][j] = __builtin_amdgcn_mfma_f32_16x16x32_bf16(a[i], b3[j], acc3[i][j], 0, 0, 0);
        }
    }
  }

#pragma unroll
  for (int i = 0; i < 4; ++i) {
#pragma unroll
    for (int rr = 0; rr < 4; ++rr) {
      int slot = t0 + wm * 64 + i * 16 + lq * 4 + rr;
      if (slot < n_e) {
        unsigned short* orow = hbuf + (size_t)(nbase + slot) * I_DIM + i0 + wn * 64 + lm;
#pragma unroll
        for (int j = 0; j < 4; ++j) {
          float g = acc1[i][j][rr], u = acc3[i][j][rr];
          float hv = (g / (1.f + __expf(-g))) * u;
          orow[j * 16] = f2bf(hv);
        }
      }
    }
  }
}

// ---------------- GEMM2: 64 slots x 128 H, BK=64, split-K=2, 4-plane partial ----------------
__global__ __launch_bounds__(256, 4) void gemm2(
    const unsigned short* __restrict__ hbuf,
    const unsigned short* __restrict__ w2t,
    const int* __restrict__ counts,
    const int* __restrict__ list_tok,
    const float* __restrict__ list_w,
    float* __restrict__ partial)
{
  __shared__ __align__(16) char smem[24576];
  int e = blockIdx.z;
  int nbase = 0;
#pragma unroll
  for (int i = 0; i < 8; ++i) if (i < e) nbase += counts[i];
  int n_e = counts[e];
  int ts = blockIdx.y >> 1, kh = blockIdx.y & 1;
  int t0 = ts * 64;
  if (t0 >= n_e) return;
  int h0 = blockIdx.x * 128;
  int k0 = kh * (I_DIM / 2);

  char* As = smem;           // 2 panels x 4KB
  char* Bs = smem + 8192;    // 2 panels x 8KB

  int tid = threadIdx.x;
  int r2 = tid >> 2;
  int seg = (tid & 3) * 8;

  int sr = t0 + r2; if (sr >= n_e) sr = n_e - 1;
  const char* gA  = (const char*)(hbuf + (size_t)(nbase + sr) * I_DIM + k0 + seg);
  const char* gB0 = (const char*)(w2t + ((size_t)e * H_DIM + h0 + r2) * I_DIM + k0 + seg);
  const char* gB1 = (const char*)(w2t + ((size_t)e * H_DIM + h0 + 64 + r2) * I_DIM + k0 + seg);

  int w = tid >> 6, lane = tid & 63, lm = lane & 15, lq = lane >> 4;
  int wm = w & 1, wn = (w >> 1) * 64;

  f32x4 acc[2][4];
#pragma unroll
  for (int i = 0; i < 2; ++i)
#pragma unroll
    for (int j = 0; j < 4; ++j) acc[i][j] = (f32x4){0,0,0,0};

  for (int kb = 0; kb < I_DIM / 2; kb += 64) {
    __syncthreads();
    gld16(gA + kb * 2,       As + tid * 16);
    gld16(gA + kb * 2 + 64,  As + 4096 + tid * 16);
    gld16(gB0 + kb * 2,      Bs + tid * 16);
    gld16(gB1 + kb * 2,      Bs + 4096 + tid * 16);
    gld16(gB0 + kb * 2 + 64, Bs + 8192 + tid * 16);
    gld16(gB1 + kb * 2 + 64, Bs + 12288 + tid * 16);
    __syncthreads();
#pragma unroll
    for (int s = 0; s < 2; ++s) {
      bf16x8 a[2], b[4];
#pragma unroll
      for (int i = 0; i < 2; ++i)
        a[i] = *(const bf16x8*)(As + s * 4096 + ((wm * 32 + i * 16 + lm) * 32 + lq * 8) * 2);
#pragma unroll
      for (int j = 0; j < 4; ++j)
        b[j] = *(const bf16x8*)(Bs + s * 8192 + ((wn + j * 16 + lm) * 32 + lq * 8) * 2);
#pragma unroll
      for (int i = 0; i < 2; ++i)
#pragma unroll
        for (int j = 0; j < 4; ++j)
          acc[i][j] = __builtin_amdgcn_mfma_f32_16x16x32_bf16(a[i], b[j], acc[i][j], 0, 0, 0);
    }
  }

  int entv[2][4]; float wtv[2][4];
#pragma unroll
  for (int i = 0; i < 2; ++i)
#pragma unroll
    for (int rr = 0; rr < 4; ++rr) {
      int slot = t0 + wm * 32 + i * 16 + lq * 4 + rr;
      if (slot < n_e) { entv[i][rr] = list_tok[nbase + slot]; wtv[i][rr] = list_w[nbase + slot]; }
      else entv[i][rr] = -1;
    }
#pragma unroll
  for (int i = 0; i < 2; ++i)
#pragma unroll
    for (int j = 0; j < 4; ++j)
#pragma unroll
      for (int rr = 0; rr < 4; ++rr) {
        if (entv[i][rr] >= 0) {
          int t = entv[i][rr] >> 1, kk = entv[i][rr] & 1;
          int plane = kh * 2 + kk;
          partial[((size_t)plane * T_TOK + t) * H_DIM + h0 + wn + j * 16 + lm] =
              acc[i][j][rr] * wtv[i][rr];
        }
      }
}

// ---------------- out = sum of 4 partial planes ----------------
__global__ __launch_bounds__(256) void combine4(const float* __restrict__ partial,
                                                float* __restrict__ out)
{
  const size_t P = (size_t)T_TOK * H_DIM;
  size_t i = (size_t)(blockIdx.x * 256 + threadIdx.x) * 4;
  float4 a = *(const float4*)(partial + i);
  float4 b = *(const float4*)(partial + P + i);
  float4 c = *(const float4*)(partial + 2 * P + i);
  float4 d = *(const float4*)(partial + 3 * P + i);
  float4 o;
  o.x = a.x + b.x + c.x + d.x;
  o.y = a.y + b.y + c.y + d.y;
  o.z = a.z + b.z + c.z + d.z;
  o.w = a.w + b.w + c.w + d.w;
  *(float4*)(out + i) = o;
}

extern "C" void kernel_launch(void* const* d_in, const int* in_sizes, int n_in,
                              void* d_out, int out_size, void* d_ws, size_t ws_size,
                              hipStream_t stream) {
  const float* x  = (const float*)d_in[0];
  const float* gw = (const float*)d_in[1];
  const float* gb = (const float*)d_in[2];
  const float* w1 = (const float*)d_in[3];
  const float* w3 = (const float*)d_in[4];
  const float* w2 = (const float*)d_in[5];
  float* out = (float*)d_out;

  char* ws = (char*)d_ws;
  int*   counts   = (int*)(ws);            // 8 ints
  int*   rec_e    = (int*)(ws + 128);      // 4096 ints
  float* rec_w    = (float*)(ws + 16512);  // 4096 floats
  int*   list_tok = (int*)(ws + 32896);    // 4096 ints
  float* list_w   = (float*)(ws + 49280);  // 4096 floats
  const size_t MB = 1024ull * 1024ull;
  unsigned short* xb   = (unsigned short*)(ws + 1 * MB);    // 4 MB
  unsigned short* w1t  = (unsigned short*)(ws + 5 * MB);    // 32 MB  [E][I][H]
  float* partial       = (float*)(ws + 5 * MB);             // 32 MB  [4][T][H] (aliases w1t; dead after gemm1_t2)
  unsigned short* w3t  = (unsigned short*)(ws + 37 * MB);   // 32 MB  [E][I][H]
  unsigned short* w2t  = (unsigned short*)(ws + 69 * MB);   // 32 MB  [E][H][I]
  unsigned short* hbuf = (unsigned short*)(ws + 101 * MB);  // 16 MB  [4096][I]

  gate_t13<<<512 + 4096, 256, 0, stream>>>(x, gw, gb, rec_e, rec_w, xb, w1, w3, w1t, w3t);
  route8<<<8, 256, 0, stream>>>(rec_e, rec_w, counts, list_tok, list_w);
  gemm1_t2<<<4096 + 2048, 256, 0, stream>>>(xb, w1t, w3t, counts, list_tok, hbuf, w2, w2t);
  gemm2<<<dim3(H_DIM / 128, 64, E_NUM), 256, 0, stream>>>(hbuf, w2t, counts, list_tok, list_w, partial);
  combine4<<<(T_TOK * H_DIM) / (256 * 4), 256, 0, stream>>>(partial, out);
}